// Round 5
// baseline (374.372 us; speedup 1.0000x reference)
//
#include <hip/hip_runtime.h>

typedef unsigned short ushort_t;
typedef unsigned int uint_t;
typedef unsigned char uchar_t;
typedef unsigned long long ull_t;

#define N_NODES 50000
#define N_EDGES 800000
#define HID 128
#define NGRAPH 64
#define N_RT 3125     // row tiles of 16 nodes
#define NBKT 196      // coarse buckets of 256 nodes
#define CHUNK 4096    // edges per pass-A block
#define NB_TEMP 3125  // temporal blocks (x2048 elems)
#define NB_WS 512     // wsplit blocks
#define NB_GS 196     // gstart scan blocks
#define NB_GEMM 1564  // 4*391
#define BCAP 6144     // passB LDS stage capacity (mean 4096 + 32 sigma)
#define BMAX 8192     // arena slot per bucket (mean + 64 sigma)

typedef __attribute__((ext_vector_type(8))) short short8;
typedef __attribute__((ext_vector_type(4))) float float4v;
typedef __attribute__((ext_vector_type(2))) float float2v;

// ---------- bf16 helpers ----------
__device__ __forceinline__ float bf2f(uint_t u) {
    union { uint_t i; float f; } v; v.i = u << 16; return v.f;
}
__device__ __forceinline__ ushort_t f2bf(float f) {
    union { float f; uint_t i; } v; v.f = f;
    uint_t r = v.i + 0x7FFFu + ((v.i >> 16) & 1u);
    return (ushort_t)(r >> 16);
}

// ---------- fp8 e4m3 helpers ----------
__device__ __forceinline__ void fp8x4_dec2(uint_t w, float2v* o) {
    o[0] = __builtin_amdgcn_cvt_pk_f32_fp8(w, false);
    o[1] = __builtin_amdgcn_cvt_pk_f32_fp8(w, true);
}
__device__ __forceinline__ void fp8x16_dec(uint4 w, float2v* o) {
    fp8x4_dec2(w.x, o);     fp8x4_dec2(w.y, o + 2);
    fp8x4_dec2(w.z, o + 4); fp8x4_dec2(w.w, o + 6);
}

// ---------- prep mega-kernel: passA + temporal + wsplit + docemb + gstart ---
__global__ __launch_bounds__(256) void prep_kernel(
    const int* __restrict__ ei,
    int* __restrict__ bucketcur, int* __restrict__ arena,
    const float* __restrict__ x, const float* __restrict__ ts,
    ushort_t* __restrict__ h,
    const float* __restrict__ Wq1, const float* __restrict__ Wk1,
    const float* __restrict__ Wv1, const float* __restrict__ Ws1,
    const float* __restrict__ Wq2, const float* __restrict__ Wk2,
    const float* __restrict__ Wv2, const float* __restrict__ Ws2,
    const float* __restrict__ bq1, const float* __restrict__ bk1,
    const float* __restrict__ bv1, const float* __restrict__ bs1,
    const float* __restrict__ bq2, const float* __restrict__ bk2,
    const float* __restrict__ bv2, const float* __restrict__ bs2,
    ushort_t* __restrict__ WF, float* __restrict__ bias_cat,
    const float* __restrict__ doc, const float* __restrict__ Wdoc,
    const float* __restrict__ bdoc, float* __restrict__ docemb,
    const int* __restrict__ batch, int* __restrict__ gstart) {
    __shared__ int hist[NBKT];
    __shared__ int lofs[NBKT];
    __shared__ int lcur[NBKT];
    __shared__ int gbase[NBKT];
    __shared__ int sbuf[256];
    __shared__ uint_t staging[CHUNK];
    __shared__ int tot_s;

    int blk = blockIdx.x;
    int t = threadIdx.x;

    if (blk < NBKT) {
        // ---------------- pass A ----------------
        if (t < NBKT) hist[t] = 0;
        __syncthreads();
        int e0 = blk * CHUNK;
        int srcs[16], dsts[16];
        #pragma unroll
        for (int i = 0; i < 16; i++) {
            int idx = e0 + i * 256 + t;
            bool v = idx < N_EDGES;
            srcs[i] = v ? ei[idx] : -1;
            dsts[i] = v ? ei[N_EDGES + idx] : -1;
            if (v) atomicAdd(&hist[dsts[i] >> 8], 1);
        }
        __syncthreads();
        int hv = (t < NBKT) ? hist[t] : 0;
        sbuf[t] = hv;
        __syncthreads();
        #pragma unroll
        for (int s = 1; s < 256; s <<= 1) {
            int add = (t >= s) ? sbuf[t - s] : 0;
            __syncthreads();
            sbuf[t] += add;
            __syncthreads();
        }
        if (t < NBKT) {
            lofs[t] = sbuf[t] - hv;
            lcur[t] = sbuf[t] - hv;
        }
        if (t == NBKT - 1) tot_s = sbuf[NBKT - 1];
        __syncthreads();
        #pragma unroll
        for (int i = 0; i < 16; i++) {
            if (srcs[i] >= 0) {
                int bkt = dsts[i] >> 8;
                int pos = atomicAdd(&lcur[bkt], 1);
                staging[pos] = ((uint_t)bkt << 24) | ((uint_t)(dsts[i] & 255) << 16)
                             | (uint_t)srcs[i];
            }
        }
        __syncthreads();
        if (t < NBKT) {
            int hcnt = hist[t];
            gbase[t] = t * BMAX + (hcnt ? atomicAdd(&bucketcur[t], hcnt) : 0);
        }
        __syncthreads();
        int tot = tot_s;
        for (int i = t; i < tot; i += 256) {
            uint_t e = staging[i];
            int bkt = e >> 24;
            arena[gbase[bkt] + (i - lofs[bkt])] = (int)(e & 0xFFFFFF);
        }
    } else if (blk < NBKT + NB_TEMP) {
        // ---------------- temporal (2048 elems/block) ----------------
        int base = (blk - NBKT) * 2048;
        #pragma unroll
        for (int u = 0; u < 8; u++) {
            int tid = base + u * 256 + t;
            int rt   = tid >> 11;
            int kt   = (tid >> 9) & 3;
            int lane = (tid >> 3) & 63;
            int j    = tid & 7;
            int n = rt * 16 + (lane & 15);
            int c = kt * 32 + (lane >> 4) * 8 + j;
            float tv = ts[n];
            const float coef = -0.07195570687f;  // -ln(10000)/128
            float ang = tv * __expf((float)(c & ~1) * coef);
            float pe = (c & 1) ? __cosf(ang) : __sinf(ang);
            h[tid] = f2bf(x[n * 128 + c] + pe);
        }
    } else if (blk < NBKT + NB_TEMP + NB_WS) {
        // ---------------- wsplit (Q weights+bias pre-scaled by 1/8) --------
        int tid = (blk - NBKT - NB_TEMP) * 256 + t;  // 0..131071
        int j    = tid & 7;
        int lane = (tid >> 3) & 63;
        int kt   = (tid >> 9) & 3;
        int cgy  = (tid >> 11) & 31;
        int L    = tid >> 16;
        int col = cgy * 16 + (lane & 15);
        int k   = kt * 32 + (lane >> 4) * 8 + j;
        int mat = col >> 7, c = col & 127;
        const float* W = (L == 0)
            ? ((mat == 0) ? Wq1 : (mat == 1) ? Wk1 : (mat == 2) ? Wv1 : Ws1)
            : ((mat == 0) ? Wq2 : (mat == 1) ? Wk2 : (mat == 2) ? Wv2 : Ws2);
        size_t base = (size_t)L * 65536 + (size_t)cgy * 2048 + (size_t)kt * 512;
        float wv = W[k * 128 + c];
        if (mat == 0) wv *= 0.125f;           // fold q-scale (exact in bf16)
        WF[base + lane * 8 + j] = f2bf(wv);
        if (kt == 0 && (lane >> 4) == 0 && j == 0) {
            const float* b = (L == 0)
                ? ((mat == 0) ? bq1 : (mat == 1) ? bk1 : (mat == 2) ? bv1 : bs1)
                : ((mat == 0) ? bq2 : (mat == 1) ? bk2 : (mat == 2) ? bv2 : bs2);
            float bb = b[c];
            if (mat == 0) bb *= 0.125f;
            bias_cat[L * 512 + col] = bb;
        }
    } else if (blk < NBKT + NB_TEMP + NB_WS + NGRAPH) {
        // ---------------- docemb ----------------
        int b = blk - NBKT - NB_TEMP - NB_WS;   // 0..63
        int c = t & 127, half = t >> 7;
        float* red = (float*)staging;           // reuse LDS
        float acc = (half == 0) ? bdoc[c] : 0.f;
        int k0 = half * 256;
        #pragma unroll 8
        for (int k = 0; k < 256; k++)
            acc += doc[b * 512 + k0 + k] * Wdoc[(size_t)(k0 + k) * 128 + c];
        red[t] = acc;
        __syncthreads();
        if (t < 128) docemb[b * 128 + c] = fmaxf(red[t] + red[t + 128], 0.f);
    } else {
        // ---------------- gstart scan (batch is sorted) ----------------
        int gblk = blk - NBKT - NB_TEMP - NB_WS - NGRAPH;  // 0..195
        int i = gblk * 256 + t;
        if (i < N_NODES) {
            int bi = batch[i];
            int bp = (i == 0) ? -1 : batch[i - 1];
            if (bi != bp) {
                for (int g = bp + 1; g <= bi; g++) gstart[g] = i;
            }
            if (i == N_NODES - 1) {
                for (int g = bi + 1; g <= NGRAPH; g++) gstart[g] = N_NODES;
            }
        }
    }
}

// ---------- shared gemm body: swapped-operand MFMA, vectorized epilogue -----
__device__ __forceinline__ void gemm_body(
    int rp, int cg0, int lane,
    const ushort_t* __restrict__ hf, const ushort_t* __restrict__ WF,
    const float* __restrict__ bias_cat,
    ushort_t* __restrict__ qsb, uchar_t* __restrict__ kv8) {
    int rt0 = rp * 2;
    if (rt0 >= N_RT) return;
    int rt1 = rt0 + 1;
    int rt1c = (rt1 < N_RT) ? rt1 : rt0;

    short8 a0[4], a1[4];
    {
        const ushort_t* b0 = hf + (size_t)rt0 * 2048 + lane * 8;
        const ushort_t* b1 = hf + (size_t)rt1c * 2048 + lane * 8;
        #pragma unroll
        for (int kt = 0; kt < 4; kt++) {
            a0[kt] = *reinterpret_cast<const short8*>(b0 + kt * 512);
            a1[kt] = *reinterpret_cast<const short8*>(b1 + kt * 512);
        }
    }

    const ushort_t* wfl = WF + (size_t)cg0 * 2048 + lane * 8;
    short8 bh[4];
    #pragma unroll
    for (int kt = 0; kt < 4; kt++)
        bh[kt] = *reinterpret_cast<const short8*>(wfl + kt * 512);

    int m = lane & 15;        // node within tile (C col after swap)
    int quad = lane >> 4;     // channel quad   (C row group after swap)
    size_t node0 = (size_t)rt0 * 16 + m;
    size_t node1 = (size_t)rt1 * 16 + m;

    #pragma unroll 2
    for (int cg = 0; cg < 8; cg++) {
        short8 bn[4];
        if (cg < 7) {
            const ushort_t* fpn = wfl + (size_t)(cg + 1) * 2048;
            #pragma unroll
            for (int kt = 0; kt < 4; kt++)
                bn[kt] = *reinterpret_cast<const short8*>(fpn + kt * 512);
        }
        float4v acc0 = {0.f, 0.f, 0.f, 0.f};
        float4v acc1 = {0.f, 0.f, 0.f, 0.f};
        #pragma unroll
        for (int kt = 0; kt < 4; kt++) {
            acc0 = __builtin_amdgcn_mfma_f32_16x16x32_bf16(bh[kt], a0[kt], acc0, 0, 0, 0);
            acc1 = __builtin_amdgcn_mfma_f32_16x16x32_bf16(bh[kt], a1[kt], acc1, 0, 0, 0);
        }
        int col0 = (cg0 + cg) * 16;
        int chq = col0 + quad * 4;          // global column of acc[0]
        float4 b4 = *reinterpret_cast<const float4*>(bias_cat + chq);
        int mat = col0 >> 7;
        {
            float v0 = acc0[0] + b4.x, v1 = acc0[1] + b4.y;
            float v2 = acc0[2] + b4.z, v3 = acc0[3] + b4.w;
            if (mat == 0 || mat == 3) {
                uint_t lo, hi;
                asm("v_cvt_pk_bf16_f32 %0, %1, %2" : "=v"(lo) : "v"(v0), "v"(v1));
                asm("v_cvt_pk_bf16_f32 %0, %1, %2" : "=v"(hi) : "v"(v2), "v"(v3));
                int cq = (mat == 0) ? chq : (chq - 256);   // S -> [128,256)
                uint2 pk; pk.x = lo; pk.y = hi;
                *reinterpret_cast<uint2*>(qsb + node0 * 256 + cq) = pk;
            } else {
                int w = __builtin_amdgcn_cvt_pk_fp8_f32(v0, v1, 0, false);
                w = __builtin_amdgcn_cvt_pk_fp8_f32(v2, v3, w, true);
                *reinterpret_cast<uint_t*>(kv8 + node0 * 256 + (chq - 128)) = (uint_t)w;
            }
        }
        if (rt1 < N_RT) {
            float v0 = acc1[0] + b4.x, v1 = acc1[1] + b4.y;
            float v2 = acc1[2] + b4.z, v3 = acc1[3] + b4.w;
            if (mat == 0 || mat == 3) {
                uint_t lo, hi;
                asm("v_cvt_pk_bf16_f32 %0, %1, %2" : "=v"(lo) : "v"(v0), "v"(v1));
                asm("v_cvt_pk_bf16_f32 %0, %1, %2" : "=v"(hi) : "v"(v2), "v"(v3));
                int cq = (mat == 0) ? chq : (chq - 256);
                uint2 pk; pk.x = lo; pk.y = hi;
                *reinterpret_cast<uint2*>(qsb + node1 * 256 + cq) = pk;
            } else {
                int w = __builtin_amdgcn_cvt_pk_fp8_f32(v0, v1, 0, false);
                w = __builtin_amdgcn_cvt_pk_fp8_f32(v2, v3, w, true);
                *reinterpret_cast<uint_t*>(kv8 + node1 * 256 + (chq - 128)) = (uint_t)w;
            }
        }
        #pragma unroll
        for (int kt = 0; kt < 4; kt++) bh[kt] = bn[kt];
    }
}

// ---------- fused: passB (off+csr build) + gemm L1 + fusdoc -----------------
__global__ __launch_bounds__(256) void g1_kernel(
    int* __restrict__ off, const int* __restrict__ arena,
    const int* __restrict__ bucketcur, int* __restrict__ csr,
    const ushort_t* __restrict__ hf, const ushort_t* __restrict__ WF,
    const float* __restrict__ bias_cat,
    ushort_t* __restrict__ qsb, uchar_t* __restrict__ kv8,
    const float* __restrict__ docemb, const float* __restrict__ Wfus,
    const float* __restrict__ bfus, float* __restrict__ fusdoc) {
    __shared__ uint_t smem[BCAP + 1024];
    __shared__ int bbase_s;
    int blk = blockIdx.x;
    int t = threadIdx.x;
    if (blk < NBKT) {
        // ---- passB: derive off[] + exact csr from arena bucket ----
        uint_t* stage = smem;
        int* lcnt = (int*)(smem + BCAP);
        int* exc  = (int*)(smem + BCAP + 256);
        int* lcur = (int*)(smem + BCAP + 512);
        int* sb   = (int*)(smem + BCAP + 768);
        int bc = (t < NBKT) ? bucketcur[t] : 0;
        sb[t] = bc;
        __syncthreads();
        #pragma unroll
        for (int s = 1; s < 256; s <<= 1) {
            int a = (t >= s) ? sb[t - s] : 0;
            __syncthreads();
            sb[t] += a;
            __syncthreads();
        }
        if (t == 0) bbase_s = (blk == 0) ? 0 : sb[blk - 1];
        lcnt[t] = 0; lcur[t] = 0;
        __syncthreads();
        int bbase = bbase_s;
        int size = bucketcur[blk];
        int abase = blk * BMAX;
        int lim = (size < BCAP) ? size : BCAP;
        for (int i = t; i < lim; i += 256) stage[i] = (uint_t)arena[abase + i];
        __syncthreads();
        for (int i = t; i < size; i += 256) {
            uint_t e = (i < BCAP) ? stage[i] : (uint_t)arena[abase + i];
            atomicAdd(&lcnt[(e >> 16) & 255], 1);
        }
        __syncthreads();
        int v = lcnt[t];
        sb[t] = v;
        __syncthreads();
        #pragma unroll
        for (int s = 1; s < 256; s <<= 1) {
            int a = (t >= s) ? sb[t - s] : 0;
            __syncthreads();
            sb[t] += a;
            __syncthreads();
        }
        exc[t] = sb[t] - v;
        int n0 = blk * 256;
        if (n0 + t < N_NODES) off[n0 + t] = bbase + sb[t] - v;
        if (blk == NBKT - 1 && t == 0) off[N_NODES] = N_EDGES;
        __syncthreads();
        for (int i = t; i < size; i += 256) {
            uint_t e = (i < BCAP) ? stage[i] : (uint_t)arena[abase + i];
            int dlow = (e >> 16) & 255;
            int src = (int)(e & 0xFFFF);
            int pos = exc[dlow] + atomicAdd(&lcur[dlow], 1);
            csr[bbase + pos] = src << 8;   // byte offset into kv8
        }
    } else if (blk < NBKT + NB_GEMM) {
        int blk2 = blk - NBKT;           // 0..1563
        int y = blk2 / 391, bx = blk2 % 391;
        int wave = t >> 6, lane = t & 63;
        gemm_body(bx * 4 + wave, y * 8, lane, hf, WF, bias_cat, qsb, kv8);
    } else {
        // ---- fusdoc[b][c] = bfus[c] + docemb[b] @ Wfus[128:256] ----
        int b = blk - NBKT - NB_GEMM;    // 0..63
        int c = t & 127, half = t >> 7;
        float* de = (float*)smem;
        float* red = (float*)smem + 128;
        if (t < 128) de[t] = docemb[b * 128 + t];
        __syncthreads();
        float acc = (half == 0) ? bfus[c] : 0.f;
        int k0 = half * 64;
        #pragma unroll 8
        for (int k = 0; k < 64; k++)
            acc += de[k0 + k] * Wfus[(size_t)(128 + k0 + k) * 128 + c];
        red[t] = acc;
        __syncthreads();
        if (t < 128) fusdoc[b * 128 + c] = red[t] + red[t + 128];
    }
}

// ---------- plain gemm (layer 2) ----------
__global__ __launch_bounds__(256) void gemm_qkvs(
    const ushort_t* __restrict__ hf,
    const ushort_t* __restrict__ WF,
    const float* __restrict__ bias_cat,
    ushort_t* __restrict__ qsb, uchar_t* __restrict__ kv8) {
    int t = threadIdx.x;
    int wave = t >> 6, lane = t & 63;
    gemm_body(blockIdx.x * 4 + wave, blockIdx.y * 8, lane,
              hf, WF, bias_cat, qsb, kv8);
}

// ---------- fused per-node attention + skip + BN + relu -> h (frag-major) ----
// 8 lanes per edge (16B uint4 K/V loads), 16 edges in flight per iteration.
// Halves serial gather rounds vs the 16-lane layout; alpha lands per-head
// per-lane after a 2-hop shuffle reduce.
__global__ __launch_bounds__(256) void node_attn_bn(
    const int* __restrict__ off, const int* __restrict__ csr_src,
    const ushort_t* __restrict__ qsb, const uchar_t* __restrict__ kv8,
    const float* __restrict__ bng, const float* __restrict__ bnb,
    const float* __restrict__ bnm, const float* __restrict__ bnv,
    ushort_t* __restrict__ h) {
    int wave = threadIdx.x >> 6;
    int n = blockIdx.x * 4 + wave;
    if (n >= N_NODES) return;
    int lane = threadIdx.x & 63;
    int slot = lane >> 3, l8 = lane & 7;
    int c0 = l8 * 16;                 // this lane's 16 channels

    const ushort_t* row_qs = qsb + (size_t)n * 256;
    float2v q2[8];
    {
        uint4 qu0 = *reinterpret_cast<const uint4*>(row_qs + c0);
        uint4 qu1 = *reinterpret_cast<const uint4*>(row_qs + c0 + 8);
        q2[0].x = bf2f(qu0.x & 0xffff); q2[0].y = bf2f(qu0.x >> 16);
        q2[1].x = bf2f(qu0.y & 0xffff); q2[1].y = bf2f(qu0.y >> 16);
        q2[2].x = bf2f(qu0.z & 0xffff); q2[2].y = bf2f(qu0.z >> 16);
        q2[3].x = bf2f(qu0.w & 0xffff); q2[3].y = bf2f(qu0.w >> 16);
        q2[4].x = bf2f(qu1.x & 0xffff); q2[4].y = bf2f(qu1.x >> 16);
        q2[5].x = bf2f(qu1.y & 0xffff); q2[5].y = bf2f(qu1.y >> 16);
        q2[6].x = bf2f(qu1.z & 0xffff); q2[6].y = bf2f(qu1.z >> 16);
        q2[7].x = bf2f(qu1.w & 0xffff); q2[7].y = bf2f(qu1.w >> 16);
    }

    int e0 = off[n], e1 = off[n + 1];
    float l = 0.f;
    float2v o2[8];
    #pragma unroll
    for (int i = 0; i < 8; i++) o2[i] = (float2v){0.f, 0.f};

    // software pipeline: indices + K/V rows one iteration ahead
    int src_a = (e0 + slot < e1) ? csr_src[e0 + slot] : 0;
    int src_b = (e0 + 8 + slot < e1) ? csr_src[e0 + 8 + slot] : 0;
    uint4 kua, vua, kub, vub;
    {
        const uchar_t* kpa = kv8 + (uint_t)src_a;
        const uchar_t* kpb = kv8 + (uint_t)src_b;
        kua = *reinterpret_cast<const uint4*>(kpa + c0);
        vua = *reinterpret_cast<const uint4*>(kpa + 128 + c0);
        kub = *reinterpret_cast<const uint4*>(kpb + c0);
        vub = *reinterpret_cast<const uint4*>(kpb + 128 + c0);
    }

    for (int p = e0; p < e1; p += 16) {
        bool va = (p + slot) < e1, vb = (p + 8 + slot) < e1;
        int na = p + 16 + slot, nb = p + 24 + slot;
        int nsa = (na < e1) ? csr_src[na] : 0;
        int nsb = (nb < e1) ? csr_src[nb] : 0;
        const uchar_t* kpa_n = kv8 + (uint_t)nsa;
        const uchar_t* kpb_n = kv8 + (uint_t)nsb;
        uint4 kua_n = *reinterpret_cast<const uint4*>(kpa_n + c0);
        uint4 vua_n = *reinterpret_cast<const uint4*>(kpa_n + 128 + c0);
        uint4 kub_n = *reinterpret_cast<const uint4*>(kpb_n + c0);
        uint4 vub_n = *reinterpret_cast<const uint4*>(kpb_n + 128 + c0);

        // decode K, dot over this lane's 16 channels
        float2v ka[8], kb[8];
        fp8x16_dec(kua, ka);
        fp8x16_dec(kub, kb);
        float2v da2 = q2[0] * ka[0];
        float2v db2 = q2[0] * kb[0];
        #pragma unroll
        for (int i = 1; i < 8; i++) {
            da2 += q2[i] * ka[i];
            db2 += q2[i] * kb[i];
        }
        float da = da2.x + da2.y;
        float db = db2.x + db2.y;
        // 4-lane (= one head) reduce: lanes l8 0-3 head0, 4-7 head1
        da += __shfl_xor(da, 1);  db += __shfl_xor(db, 1);
        da += __shfl_xor(da, 2);  db += __shfl_xor(db, 2);
        float pea = va ? __expf(da) : 0.f;
        float peb = vb ? __expf(db) : 0.f;
        l += pea + peb;
        // decode V, accumulate
        float2v wa[8], wb[8];
        fp8x16_dec(vua, wa);
        fp8x16_dec(vub, wb);
        float2v pa; pa.x = pea; pa.y = pea;
        float2v pb; pb.x = peb; pb.y = peb;
        #pragma unroll
        for (int i = 0; i < 8; i++) {
            o2[i] += pa * wa[i];
            o2[i] += pb * wb[i];
        }
        kua = kua_n; vua = vua_n; kub = kub_n; vub = vub_n;
    }
    // reduce across the 8 slots
    #pragma unroll
    for (int offx = 8; offx <= 32; offx <<= 1) {
        l += __shfl_xor(l, offx);
        #pragma unroll
        for (int i = 0; i < 8; i++) {
            o2[i].x += __shfl_xor(o2[i].x, offx);
            o2[i].y += __shfl_xor(o2[i].y, offx);
        }
    }

    if (slot == 0) {
        float inv = 1.f / (l + 1e-16f);
        float o[16];
        #pragma unroll
        for (int i = 0; i < 8; i++) { o[2 * i] = o2[i].x; o[2 * i + 1] = o2[i].y; }
        float sv[16];
        {
            uint4 su0 = *reinterpret_cast<const uint4*>(row_qs + 128 + c0);
            uint4 su1 = *reinterpret_cast<const uint4*>(row_qs + 128 + c0 + 8);
            sv[0] = bf2f(su0.x & 0xffff);  sv[1] = bf2f(su0.x >> 16);
            sv[2] = bf2f(su0.y & 0xffff);  sv[3] = bf2f(su0.y >> 16);
            sv[4] = bf2f(su0.z & 0xffff);  sv[5] = bf2f(su0.z >> 16);
            sv[6] = bf2f(su0.w & 0xffff);  sv[7] = bf2f(su0.w >> 16);
            sv[8] = bf2f(su1.x & 0xffff);  sv[9] = bf2f(su1.x >> 16);
            sv[10] = bf2f(su1.y & 0xffff); sv[11] = bf2f(su1.y >> 16);
            sv[12] = bf2f(su1.z & 0xffff); sv[13] = bf2f(su1.z >> 16);
            sv[14] = bf2f(su1.w & 0xffff); sv[15] = bf2f(su1.w >> 16);
        }
        float gv[16], bv[16], mv[16], vr[16];
        #pragma unroll
        for (int q = 0; q < 4; q++) {
            *reinterpret_cast<float4*>(gv + 4 * q) = *reinterpret_cast<const float4*>(bng + c0 + 4 * q);
            *reinterpret_cast<float4*>(bv + 4 * q) = *reinterpret_cast<const float4*>(bnb + c0 + 4 * q);
            *reinterpret_cast<float4*>(mv + 4 * q) = *reinterpret_cast<const float4*>(bnm + c0 + 4 * q);
            *reinterpret_cast<float4*>(vr + 4 * q) = *reinterpret_cast<const float4*>(bnv + c0 + 4 * q);
        }
        uint_t hw[8];
        #pragma unroll
        for (int i = 0; i < 16; i++) {
            float val = fmaxf(o[i] * inv + sv[i], 0.f);
            val = (val - mv[i]) * rsqrtf(vr[i] + 1e-5f) * gv[i] + bv[i];
            val = fmaxf(val, 0.f);
            ushort_t hb = f2bf(val);
            if (i & 1) hw[i >> 1] |= (uint_t)hb << 16;
            else       hw[i >> 1] = hb;
        }
        int rt = n >> 4, mnode = n & 15;
        int kt = l8 >> 1, qd0 = (l8 & 1) * 2;
        size_t base = (size_t)rt * 2048 + (size_t)kt * 512;
        uint4 h0; h0.x = hw[0]; h0.y = hw[1]; h0.z = hw[2]; h0.w = hw[3];
        uint4 h1; h1.x = hw[4]; h1.y = hw[5]; h1.z = hw[6]; h1.w = hw[7];
        *reinterpret_cast<uint4*>(h + base + (size_t)(mnode + 16 * qd0) * 8) = h0;
        *reinterpret_cast<uint4*>(h + base + (size_t)(mnode + 16 * (qd0 + 1)) * 8) = h1;
    }
}

// ---------- merged pool + final head (batch sorted -> per-graph ranges) -----
__global__ __launch_bounds__(256) void final_pool(
    const ushort_t* __restrict__ h, const int* __restrict__ gstart,
    const float* __restrict__ fusdoc, const float* __restrict__ Wfus,
    const float* __restrict__ Wtask, const float* __restrict__ btask,
    const float* __restrict__ Wtime, const float* __restrict__ btime,
    float* __restrict__ out) {
    __shared__ float lsum[16][136];
    __shared__ float gbuf[128], fbuf[128], red[256];
    int b = blockIdx.x, t = threadIdx.x;
    int r0 = gstart[b], r1 = gstart[b + 1];
    int o = t & 15, s = t >> 4;       // o: channel octet, s: node slot
    int kt = o >> 2, qd = o & 3;
    float f0 = 0, f1 = 0, f2 = 0, f3 = 0, f4 = 0, f5 = 0, f6 = 0, f7 = 0;
    for (int n = r0 + s; n < r1; n += 16) {
        int rt = n >> 4, mn = n & 15;
        uint4 d = *reinterpret_cast<const uint4*>(
            h + (size_t)rt * 2048 + kt * 512 + (mn + 16 * qd) * 8);
        f0 += bf2f(d.x & 0xffff); f1 += bf2f(d.x >> 16);
        f2 += bf2f(d.y & 0xffff); f3 += bf2f(d.y >> 16);
        f4 += bf2f(d.z & 0xffff); f5 += bf2f(d.z >> 16);
        f6 += bf2f(d.w & 0xffff); f7 += bf2f(d.w >> 16);
    }
    int c0 = kt * 32 + qd * 8;
    float* dst = &lsum[s][c0];
    dst[0] = f0; dst[1] = f1; dst[2] = f2; dst[3] = f3;
    dst[4] = f4; dst[5] = f5; dst[6] = f6; dst[7] = f7;
    __syncthreads();
    if (t < 128) {
        float a = 0.f;
        #pragma unroll
        for (int i = 0; i < 16; i++) a += lsum[i][t];
        gbuf[t] = a / fmaxf((float)(r1 - r0), 1.f);
    }
    __syncthreads();
    int c = t & 127, half = t >> 7;
    float f = (half == 0) ? fusdoc[b * 128 + c] : 0.f;
    int k0 = half * 64;
    #pragma unroll 8
    for (int k = 0; k < 64; k++)
        f += gbuf[k0 + k] * Wfus[(size_t)(k0 + k) * 128 + c];
    red[t] = f;
    __syncthreads();
    if (t < 128) fbuf[t] = fmaxf(red[t] + red[t + 128], 0.f);
    __syncthreads();
    if (t < 16) {
        float a = btask[t];
        #pragma unroll 8
        for (int k = 0; k < 128; k++) a += fbuf[k] * Wtask[k * 16 + t];
        out[b * 16 + t] = a;
    } else if (t == 16) {
        float a = btime[0];
        #pragma unroll 8
        for (int k = 0; k < 128; k++) a += fbuf[k] * Wtime[k];
        out[NGRAPH * 16 + b] = a;
    }
}

extern "C" void kernel_launch(void* const* d_in, const int* in_sizes, int n_in,
                              void* d_out, int out_size, void* d_ws, size_t ws_size,
                              hipStream_t stream) {
    (void)in_sizes; (void)n_in; (void)out_size; (void)ws_size;
    const float* x    = (const float*)d_in[0];
    const int*   ei   = (const int*)d_in[1];
    const int*   batch= (const int*)d_in[2];
    const float* ts   = (const float*)d_in[3];
    const float* doc  = (const float*)d_in[4];
    const float* Wq1  = (const float*)d_in[5];
    const float* bq1  = (const float*)d_in[6];
    const float* Wk1  = (const float*)d_in[7];
    const float* bk1  = (const float*)d_in[8];
    const float* Wv1  = (const float*)d_in[9];
    const float* bv1  = (const float*)d_in[10];
    const float* Ws1  = (const float*)d_in[11];
    const float* bs1  = (const float*)d_in[12];
    const float* Wq2  = (const float*)d_in[13];
    const float* bq2  = (const float*)d_in[14];
    const float* Wk2  = (const float*)d_in[15];
    const float* bk2  = (const float*)d_in[16];
    const float* Wv2  = (const float*)d_in[17];
    const float* bv2  = (const float*)d_in[18];
    const float* Ws2  = (const float*)d_in[19];
    const float* bs2  = (const float*)d_in[20];
    const float* bn1g = (const float*)d_in[21];
    const float* bn1b = (const float*)d_in[22];
    const float* bn1m = (const float*)d_in[23];
    const float* bn1v = (const float*)d_in[24];
    const float* bn2g = (const float*)d_in[25];
    const float* bn2b = (const float*)d_in[26];
    const float* bn2m = (const float*)d_in[27];
    const float* bn2v = (const float*)d_in[28];
    const float* Wdoc = (const float*)d_in[29];
    const float* bdoc = (const float*)d_in[30];
    const float* Wfus = (const float*)d_in[31];
    const float* bfus = (const float*)d_in[32];
    const float* Wtask= (const float*)d_in[33];
    const float* btask= (const float*)d_in[34];
    const float* Wtime= (const float*)d_in[35];
    const float* btime= (const float*)d_in[36];

    char* ws = (char*)d_ws;
    ushort_t* h      = (ushort_t*)(ws + 0);           // 12.8 MB
    ushort_t* qsb    = (ushort_t*)(ws + 12800000);    // 25.6 MB
    uchar_t*  kv8    = (uchar_t*)(ws + 38400000);     // 12.8 MB
    ushort_t* WF     = (ushort_t*)(ws + 51200000);    // 256 KB
    float*    biasc  = (float*)(ws + 51462144);       // 4 KB
    int*      gstart = (int*)(ws + 51466240);         // 260 B
    int*      off    = (int*)(ws + 51499264);         // 200004 B
    int*      bucketcur = (int*)(ws + 51699268);      // 784 B
    int*      arena  = (int*)(ws + 51700052);         // 196*8192*4 = 6.42 MB
    int*      csr    = (int*)(ws + 58122580);         // 3.2 MB
    float*    docemb = (float*)(ws + 61322580);       // 32 KB
    float*    fusdoc = (float*)(ws + 61355348);       // 32 KB

    float* out = (float*)d_out;

    hipMemsetAsync(bucketcur, 0, 784, stream);

    prep_kernel<<<NBKT + NB_TEMP + NB_WS + NGRAPH + NB_GS, 256, 0, stream>>>(
        ei, bucketcur, arena, x, ts, h,
        Wq1, Wk1, Wv1, Ws1, Wq2, Wk2, Wv2, Ws2,
        bq1, bk1, bv1, bs1, bq2, bk2, bv2, bs2, WF, biasc,
        doc, Wdoc, bdoc, docemb, batch, gstart);

    const size_t WF_LAYER = 65536;  // shorts per layer

    // ---- layer 1 (gemm fused with passB(off+csr) + fusdoc) ----
    g1_kernel<<<NBKT + NB_GEMM + NGRAPH, 256, 0, stream>>>(
        off, arena, bucketcur, csr, h, WF, biasc, qsb, kv8,
        docemb, Wfus, bfus, fusdoc);
    node_attn_bn<<<12500, 256, 0, stream>>>(off, csr, qsb, kv8, bn1g, bn1b, bn1m, bn1v, h);

    // ---- layer 2 ----
    gemm_qkvs<<<dim3(391, 4), 256, 0, stream>>>(h, WF + WF_LAYER, biasc + 512, qsb, kv8);
    node_attn_bn<<<12500, 256, 0, stream>>>(off, csr, qsb, kv8, bn2g, bn2b, bn2m, bn2v, h);

    // ---- merged pool + final head ----
    final_pool<<<NGRAPH, 256, 0, stream>>>(h, gstart, fusdoc, Wfus,
                                           Wtask, btask, Wtime, btime, out);
}

// Round 6
// 349.949 us; speedup vs baseline: 1.0698x; 1.0698x over previous
//
#include <hip/hip_runtime.h>

typedef unsigned short ushort_t;
typedef unsigned int uint_t;
typedef unsigned char uchar_t;
typedef unsigned long long ull_t;

#define N_NODES 50000
#define N_EDGES 800000
#define HID 128
#define NGRAPH 64
#define N_RT 3125     // row tiles of 16 nodes
#define NBKT 196      // coarse buckets of 256 nodes
#define CHUNK 4096    // edges per pass-A block
#define NB_TEMP 3125  // temporal blocks (x2048 elems)
#define NB_WS 512     // wsplit blocks
#define NB_GS 196     // gstart scan blocks
#define NB_GEMM 1564  // 4*391
#define BCAP 6144     // passB LDS stage capacity (mean 4096 + 32 sigma)
#define BMAX 8192     // arena slot per bucket (mean + 64 sigma)

typedef __attribute__((ext_vector_type(8))) short short8;
typedef __attribute__((ext_vector_type(4))) float float4v;
typedef __attribute__((ext_vector_type(2))) float float2v;

// ---------- bf16 helpers ----------
__device__ __forceinline__ float bf2f(uint_t u) {
    union { uint_t i; float f; } v; v.i = u << 16; return v.f;
}
__device__ __forceinline__ ushort_t f2bf(float f) {
    union { float f; uint_t i; } v; v.f = f;
    uint_t r = v.i + 0x7FFFu + ((v.i >> 16) & 1u);
    return (ushort_t)(r >> 16);
}

// ---------- fp8 e4m3 helpers ----------
__device__ __forceinline__ void fp8x4_dec2(uint_t w, float2v* o) {
    o[0] = __builtin_amdgcn_cvt_pk_f32_fp8(w, false);
    o[1] = __builtin_amdgcn_cvt_pk_f32_fp8(w, true);
}

// ---------- packed-f32 VOP3P ----------
__device__ __forceinline__ float2v pk_mul(float2v a, float2v b) {
    float2v d;
    asm("v_pk_mul_f32 %0, %1, %2" : "=v"(d) : "v"(a), "v"(b));
    return d;
}
__device__ __forceinline__ float2v pk_fma(float2v a, float2v b, float2v c) {
    float2v d;
    asm("v_pk_fma_f32 %0, %1, %2, %3" : "=v"(d) : "v"(a), "v"(b), "v"(c));
    return d;
}

// ---------- passA: edge binning into coarse buckets ----------
__global__ __launch_bounds__(256) void prep_edges(
    const int* __restrict__ ei,
    int* __restrict__ bucketcur, int* __restrict__ arena) {
    __shared__ int hist[NBKT];
    __shared__ int lofs[NBKT];
    __shared__ int lcur[NBKT];
    __shared__ int gbase[NBKT];
    __shared__ int sbuf[256];
    __shared__ uint_t staging[CHUNK];
    __shared__ int tot_s;
    int blk = blockIdx.x;
    int t = threadIdx.x;
    if (t < NBKT) hist[t] = 0;
    __syncthreads();
    int e0 = blk * CHUNK;
    int srcs[16], dsts[16];
    #pragma unroll
    for (int i = 0; i < 16; i++) {
        int idx = e0 + i * 256 + t;
        bool v = idx < N_EDGES;
        srcs[i] = v ? ei[idx] : -1;
        dsts[i] = v ? ei[N_EDGES + idx] : -1;
        if (v) atomicAdd(&hist[dsts[i] >> 8], 1);
    }
    __syncthreads();
    int hv = (t < NBKT) ? hist[t] : 0;
    sbuf[t] = hv;
    __syncthreads();
    #pragma unroll
    for (int s = 1; s < 256; s <<= 1) {
        int add = (t >= s) ? sbuf[t - s] : 0;
        __syncthreads();
        sbuf[t] += add;
        __syncthreads();
    }
    if (t < NBKT) {
        lofs[t] = sbuf[t] - hv;
        lcur[t] = sbuf[t] - hv;
    }
    if (t == NBKT - 1) tot_s = sbuf[NBKT - 1];
    __syncthreads();
    #pragma unroll
    for (int i = 0; i < 16; i++) {
        if (srcs[i] >= 0) {
            int bkt = dsts[i] >> 8;
            int pos = atomicAdd(&lcur[bkt], 1);
            staging[pos] = ((uint_t)bkt << 24) | ((uint_t)(dsts[i] & 255) << 16)
                         | (uint_t)srcs[i];
        }
    }
    __syncthreads();
    if (t < NBKT) {
        int hcnt = hist[t];
        gbase[t] = t * BMAX + (hcnt ? atomicAdd(&bucketcur[t], hcnt) : 0);
    }
    __syncthreads();
    int tot = tot_s;
    for (int i = t; i < tot; i += 256) {
        uint_t e = staging[i];
        int bkt = e >> 24;
        arena[gbase[bkt] + (i - lofs[bkt])] = (int)(e & 0xFFFFFF);
    }
}

// ---------- features: temporal + wsplit + docemb + gstart ----------
__global__ __launch_bounds__(256) void prep_feat(
    const float* __restrict__ x, const float* __restrict__ ts,
    ushort_t* __restrict__ h,
    const float* __restrict__ Wq1, const float* __restrict__ Wk1,
    const float* __restrict__ Wv1, const float* __restrict__ Ws1,
    const float* __restrict__ Wq2, const float* __restrict__ Wk2,
    const float* __restrict__ Wv2, const float* __restrict__ Ws2,
    const float* __restrict__ bq1, const float* __restrict__ bk1,
    const float* __restrict__ bv1, const float* __restrict__ bs1,
    const float* __restrict__ bq2, const float* __restrict__ bk2,
    const float* __restrict__ bv2, const float* __restrict__ bs2,
    ushort_t* __restrict__ WF, float* __restrict__ bias_cat,
    const float* __restrict__ doc, const float* __restrict__ Wdoc,
    const float* __restrict__ bdoc, float* __restrict__ docemb,
    const int* __restrict__ batch, int* __restrict__ gstart) {
    __shared__ float red[256];
    int blk = blockIdx.x;
    int t = threadIdx.x;
    if (blk < NB_TEMP) {
        // ---------------- temporal (2048 elems/block) ----------------
        int base = blk * 2048;
        #pragma unroll
        for (int u = 0; u < 8; u++) {
            int tid = base + u * 256 + t;
            int rt   = tid >> 11;
            int kt   = (tid >> 9) & 3;
            int lane = (tid >> 3) & 63;
            int j    = tid & 7;
            int n = rt * 16 + (lane & 15);
            int c = kt * 32 + (lane >> 4) * 8 + j;
            float tv = ts[n];
            const float coef = -0.07195570687f;  // -ln(10000)/128
            float ang = tv * __expf((float)(c & ~1) * coef);
            float pe = (c & 1) ? __cosf(ang) : __sinf(ang);
            h[tid] = f2bf(x[n * 128 + c] + pe);
        }
    } else if (blk < NB_TEMP + NB_WS) {
        // ---------------- wsplit (Q weights+bias pre-scaled by 1/8) --------
        int tid = (blk - NB_TEMP) * 256 + t;  // 0..131071
        int j    = tid & 7;
        int lane = (tid >> 3) & 63;
        int kt   = (tid >> 9) & 3;
        int cgy  = (tid >> 11) & 31;
        int L    = tid >> 16;
        int col = cgy * 16 + (lane & 15);
        int k   = kt * 32 + (lane >> 4) * 8 + j;
        int mat = col >> 7, c = col & 127;
        const float* W = (L == 0)
            ? ((mat == 0) ? Wq1 : (mat == 1) ? Wk1 : (mat == 2) ? Wv1 : Ws1)
            : ((mat == 0) ? Wq2 : (mat == 1) ? Wk2 : (mat == 2) ? Wv2 : Ws2);
        size_t base = (size_t)L * 65536 + (size_t)cgy * 2048 + (size_t)kt * 512;
        float wv = W[k * 128 + c];
        if (mat == 0) wv *= 0.125f;           // fold q-scale (exact in bf16)
        WF[base + lane * 8 + j] = f2bf(wv);
        if (kt == 0 && (lane >> 4) == 0 && j == 0) {
            const float* b = (L == 0)
                ? ((mat == 0) ? bq1 : (mat == 1) ? bk1 : (mat == 2) ? bv1 : bs1)
                : ((mat == 0) ? bq2 : (mat == 1) ? bk2 : (mat == 2) ? bv2 : bs2);
            float bb = b[c];
            if (mat == 0) bb *= 0.125f;
            bias_cat[L * 512 + col] = bb;
        }
    } else if (blk < NB_TEMP + NB_WS + NGRAPH) {
        // ---------------- docemb ----------------
        int b = blk - NB_TEMP - NB_WS;   // 0..63
        int c = t & 127, half = t >> 7;
        float acc = (half == 0) ? bdoc[c] : 0.f;
        int k0 = half * 256;
        #pragma unroll 8
        for (int k = 0; k < 256; k++)
            acc += doc[b * 512 + k0 + k] * Wdoc[(size_t)(k0 + k) * 128 + c];
        red[t] = acc;
        __syncthreads();
        if (t < 128) docemb[b * 128 + c] = fmaxf(red[t] + red[t + 128], 0.f);
    } else {
        // ---------------- gstart scan (batch is sorted) ----------------
        int gblk = blk - NB_TEMP - NB_WS - NGRAPH;  // 0..195
        int i = gblk * 256 + t;
        if (i < N_NODES) {
            int bi = batch[i];
            int bp = (i == 0) ? -1 : batch[i - 1];
            if (bi != bp) {
                for (int g = bp + 1; g <= bi; g++) gstart[g] = i;
            }
            if (i == N_NODES - 1) {
                for (int g = bi + 1; g <= NGRAPH; g++) gstart[g] = N_NODES;
            }
        }
    }
}

// ---------- passB: derive off[] + exact csr from arena buckets ----------
__global__ __launch_bounds__(256) void passb_kernel(
    int* __restrict__ off, const int* __restrict__ arena,
    const int* __restrict__ bucketcur, int* __restrict__ csr) {
    __shared__ uint_t smem[BCAP + 1024];
    __shared__ int bbase_s;
    int blk = blockIdx.x;
    int t = threadIdx.x;
    uint_t* stage = smem;
    int* lcnt = (int*)(smem + BCAP);
    int* exc  = (int*)(smem + BCAP + 256);
    int* lcur = (int*)(smem + BCAP + 512);
    int* sb   = (int*)(smem + BCAP + 768);
    int bc = (t < NBKT) ? bucketcur[t] : 0;
    sb[t] = bc;
    __syncthreads();
    #pragma unroll
    for (int s = 1; s < 256; s <<= 1) {
        int a = (t >= s) ? sb[t - s] : 0;
        __syncthreads();
        sb[t] += a;
        __syncthreads();
    }
    if (t == 0) bbase_s = (blk == 0) ? 0 : sb[blk - 1];
    lcnt[t] = 0; lcur[t] = 0;
    __syncthreads();
    int bbase = bbase_s;
    int size = bucketcur[blk];
    int abase = blk * BMAX;
    int lim = (size < BCAP) ? size : BCAP;
    for (int i = t; i < lim; i += 256) stage[i] = (uint_t)arena[abase + i];
    __syncthreads();
    for (int i = t; i < size; i += 256) {
        uint_t e = (i < BCAP) ? stage[i] : (uint_t)arena[abase + i];
        atomicAdd(&lcnt[(e >> 16) & 255], 1);
    }
    __syncthreads();
    int v = lcnt[t];
    sb[t] = v;
    __syncthreads();
    #pragma unroll
    for (int s = 1; s < 256; s <<= 1) {
        int a = (t >= s) ? sb[t - s] : 0;
        __syncthreads();
        sb[t] += a;
        __syncthreads();
    }
    exc[t] = sb[t] - v;
    int n0 = blk * 256;
    if (n0 + t < N_NODES) off[n0 + t] = bbase + sb[t] - v;
    if (blk == NBKT - 1 && t == 0) off[N_NODES] = N_EDGES;
    __syncthreads();
    for (int i = t; i < size; i += 256) {
        uint_t e = (i < BCAP) ? stage[i] : (uint_t)arena[abase + i];
        int dlow = (e >> 16) & 255;
        int src = (int)(e & 0xFFFF);
        int pos = exc[dlow] + atomicAdd(&lcur[dlow], 1);
        csr[bbase + pos] = src << 8;   // byte offset into kv8
    }
}

// ---------- shared gemm body: swapped-operand MFMA, vectorized epilogue -----
__device__ __forceinline__ void gemm_body(
    int rp, int cg0, int lane,
    const ushort_t* __restrict__ hf, const ushort_t* __restrict__ WF,
    const float* __restrict__ bias_cat,
    ushort_t* __restrict__ qsb, uchar_t* __restrict__ kv8) {
    int rt0 = rp * 2;
    if (rt0 >= N_RT) return;
    int rt1 = rt0 + 1;
    int rt1c = (rt1 < N_RT) ? rt1 : rt0;

    short8 a0[4], a1[4];
    {
        const ushort_t* b0 = hf + (size_t)rt0 * 2048 + lane * 8;
        const ushort_t* b1 = hf + (size_t)rt1c * 2048 + lane * 8;
        #pragma unroll
        for (int kt = 0; kt < 4; kt++) {
            a0[kt] = *reinterpret_cast<const short8*>(b0 + kt * 512);
            a1[kt] = *reinterpret_cast<const short8*>(b1 + kt * 512);
        }
    }

    const ushort_t* wfl = WF + (size_t)cg0 * 2048 + lane * 8;
    short8 bh[4];
    #pragma unroll
    for (int kt = 0; kt < 4; kt++)
        bh[kt] = *reinterpret_cast<const short8*>(wfl + kt * 512);

    int m = lane & 15;        // node within tile (C col after swap)
    int quad = lane >> 4;     // channel quad   (C row group after swap)
    size_t node0 = (size_t)rt0 * 16 + m;
    size_t node1 = (size_t)rt1 * 16 + m;

    #pragma unroll 2
    for (int cg = 0; cg < 8; cg++) {
        short8 bn[4];
        if (cg < 7) {
            const ushort_t* fpn = wfl + (size_t)(cg + 1) * 2048;
            #pragma unroll
            for (int kt = 0; kt < 4; kt++)
                bn[kt] = *reinterpret_cast<const short8*>(fpn + kt * 512);
        }
        float4v acc0 = {0.f, 0.f, 0.f, 0.f};
        float4v acc1 = {0.f, 0.f, 0.f, 0.f};
        #pragma unroll
        for (int kt = 0; kt < 4; kt++) {
            acc0 = __builtin_amdgcn_mfma_f32_16x16x32_bf16(bh[kt], a0[kt], acc0, 0, 0, 0);
            acc1 = __builtin_amdgcn_mfma_f32_16x16x32_bf16(bh[kt], a1[kt], acc1, 0, 0, 0);
        }
        int col0 = (cg0 + cg) * 16;
        int chq = col0 + quad * 4;          // global column of acc[0]
        float4 b4 = *reinterpret_cast<const float4*>(bias_cat + chq);
        int mat = col0 >> 7;
        {
            float v0 = acc0[0] + b4.x, v1 = acc0[1] + b4.y;
            float v2 = acc0[2] + b4.z, v3 = acc0[3] + b4.w;
            if (mat == 0 || mat == 3) {
                uint_t lo, hi;
                asm("v_cvt_pk_bf16_f32 %0, %1, %2" : "=v"(lo) : "v"(v0), "v"(v1));
                asm("v_cvt_pk_bf16_f32 %0, %1, %2" : "=v"(hi) : "v"(v2), "v"(v3));
                int cq = (mat == 0) ? chq : (chq - 256);   // S -> [128,256)
                uint2 pk; pk.x = lo; pk.y = hi;
                *reinterpret_cast<uint2*>(qsb + node0 * 256 + cq) = pk;
            } else {
                int w = __builtin_amdgcn_cvt_pk_fp8_f32(v0, v1, 0, false);
                w = __builtin_amdgcn_cvt_pk_fp8_f32(v2, v3, w, true);
                *reinterpret_cast<uint_t*>(kv8 + node0 * 256 + (chq - 128)) = (uint_t)w;
            }
        }
        if (rt1 < N_RT) {
            float v0 = acc1[0] + b4.x, v1 = acc1[1] + b4.y;
            float v2 = acc1[2] + b4.z, v3 = acc1[3] + b4.w;
            if (mat == 0 || mat == 3) {
                uint_t lo, hi;
                asm("v_cvt_pk_bf16_f32 %0, %1, %2" : "=v"(lo) : "v"(v0), "v"(v1));
                asm("v_cvt_pk_bf16_f32 %0, %1, %2" : "=v"(hi) : "v"(v2), "v"(v3));
                int cq = (mat == 0) ? chq : (chq - 256);
                uint2 pk; pk.x = lo; pk.y = hi;
                *reinterpret_cast<uint2*>(qsb + node1 * 256 + cq) = pk;
            } else {
                int w = __builtin_amdgcn_cvt_pk_fp8_f32(v0, v1, 0, false);
                w = __builtin_amdgcn_cvt_pk_fp8_f32(v2, v3, w, true);
                *reinterpret_cast<uint_t*>(kv8 + node1 * 256 + (chq - 128)) = (uint_t)w;
            }
        }
        #pragma unroll
        for (int kt = 0; kt < 4; kt++) bh[kt] = bn[kt];
    }
}

// ---------- gemm L1 + fusdoc ----------
__global__ __launch_bounds__(256) void gemm1_kernel(
    const ushort_t* __restrict__ hf, const ushort_t* __restrict__ WF,
    const float* __restrict__ bias_cat,
    ushort_t* __restrict__ qsb, uchar_t* __restrict__ kv8,
    const float* __restrict__ docemb, const float* __restrict__ Wfus,
    const float* __restrict__ bfus, float* __restrict__ fusdoc) {
    __shared__ float smem[384];
    int blk = blockIdx.x;
    int t = threadIdx.x;
    if (blk < NB_GEMM) {
        int y = blk / 391, bx = blk % 391;
        int wave = t >> 6, lane = t & 63;
        gemm_body(bx * 4 + wave, y * 8, lane, hf, WF, bias_cat, qsb, kv8);
    } else {
        // ---- fusdoc[b][c] = bfus[c] + docemb[b] @ Wfus[128:256] ----
        int b = blk - NB_GEMM;    // 0..63
        int c = t & 127, half = t >> 7;
        float* de = smem;
        float* red = smem + 128;
        if (t < 128) de[t] = docemb[b * 128 + t];
        __syncthreads();
        float acc = (half == 0) ? bfus[c] : 0.f;
        int k0 = half * 64;
        #pragma unroll 8
        for (int k = 0; k < 64; k++)
            acc += de[k0 + k] * Wfus[(size_t)(128 + k0 + k) * 128 + c];
        red[t] = acc;
        __syncthreads();
        if (t < 128) fusdoc[b * 128 + c] = red[t] + red[t + 128];
    }
}

// ---------- plain gemm (layer 2) ----------
__global__ __launch_bounds__(256) void gemm_qkvs(
    const ushort_t* __restrict__ hf,
    const ushort_t* __restrict__ WF,
    const float* __restrict__ bias_cat,
    ushort_t* __restrict__ qsb, uchar_t* __restrict__ kv8) {
    int t = threadIdx.x;
    int wave = t >> 6, lane = t & 63;
    gemm_body(blockIdx.x * 4 + wave, blockIdx.y * 8, lane,
              hf, WF, bias_cat, qsb, kv8);
}

// ---------- fused per-node attention + skip + BN + relu -> h (frag-major) ----
// csr_src holds src*256 (byte offset). 16 lanes/edge, 8 edges/iter, K/V data
// prefetched one iteration ahead, packed-f32 math. (R4-proven version.)
__global__ __launch_bounds__(256) void node_attn_bn(
    const int* __restrict__ off, const int* __restrict__ csr_src,
    const ushort_t* __restrict__ qsb, const uchar_t* __restrict__ kv8,
    const float* __restrict__ bng, const float* __restrict__ bnb,
    const float* __restrict__ bnm, const float* __restrict__ bnv,
    ushort_t* __restrict__ h) {
    int wave = threadIdx.x >> 6;
    int n = blockIdx.x * 4 + wave;
    if (n >= N_NODES) return;
    int lane = threadIdx.x & 63;
    int qtr = lane >> 4, s16 = lane & 15;
    int c0 = s16 * 8;

    const ushort_t* row_qs = qsb + (size_t)n * 256;
    float2v q2[4];
    {
        uint4 qu = *reinterpret_cast<const uint4*>(row_qs + c0);
        q2[0].x = bf2f(qu.x & 0xffff); q2[0].y = bf2f(qu.x >> 16);
        q2[1].x = bf2f(qu.y & 0xffff); q2[1].y = bf2f(qu.y >> 16);
        q2[2].x = bf2f(qu.z & 0xffff); q2[2].y = bf2f(qu.z >> 16);
        q2[3].x = bf2f(qu.w & 0xffff); q2[3].y = bf2f(qu.w >> 16);
    }

    int e0 = off[n], e1 = off[n + 1];
    float l = 0.f;
    float2v o2[4];
    o2[0] = (float2v){0.f, 0.f}; o2[1] = (float2v){0.f, 0.f};
    o2[2] = (float2v){0.f, 0.f}; o2[3] = (float2v){0.f, 0.f};

    int src_a = (e0 + qtr < e1) ? csr_src[e0 + qtr] : 0;
    int src_b = (e0 + 4 + qtr < e1) ? csr_src[e0 + 4 + qtr] : 0;
    uint2 kua, vua, kub, vub;
    {
        const uchar_t* kpa = kv8 + (uint_t)src_a;
        const uchar_t* kpb = kv8 + (uint_t)src_b;
        kua = *reinterpret_cast<const uint2*>(kpa + c0);
        vua = *reinterpret_cast<const uint2*>(kpa + 128 + c0);
        kub = *reinterpret_cast<const uint2*>(kpb + c0);
        vub = *reinterpret_cast<const uint2*>(kpb + 128 + c0);
    }

    for (int p = e0; p < e1; p += 8) {
        bool va = (p + qtr) < e1, vb = (p + 4 + qtr) < e1;
        int na = p + 8 + qtr, nb = p + 12 + qtr;
        int nsa = (na < e1) ? csr_src[na] : 0;
        int nsb = (nb < e1) ? csr_src[nb] : 0;
        const uchar_t* kpa_n = kv8 + (uint_t)nsa;
        const uchar_t* kpb_n = kv8 + (uint_t)nsb;
        uint2 kua_n = *reinterpret_cast<const uint2*>(kpa_n + c0);
        uint2 vua_n = *reinterpret_cast<const uint2*>(kpa_n + 128 + c0);
        uint2 kub_n = *reinterpret_cast<const uint2*>(kpb_n + c0);
        uint2 vub_n = *reinterpret_cast<const uint2*>(kpb_n + 128 + c0);

        float2v ka2[4], wa2[4], kb2[4], wb2[4];
        fp8x4_dec2(kua.x, ka2);  fp8x4_dec2(kua.y, ka2 + 2);
        fp8x4_dec2(kub.x, kb2);  fp8x4_dec2(kub.y, kb2 + 2);
        fp8x4_dec2(vua.x, wa2);  fp8x4_dec2(vua.y, wa2 + 2);
        fp8x4_dec2(vub.x, wb2);  fp8x4_dec2(vub.y, wb2 + 2);

        float2v da2 = pk_mul(q2[0], ka2[0]);
        float2v db2 = pk_mul(q2[0], kb2[0]);
        da2 = pk_fma(q2[1], ka2[1], da2);  db2 = pk_fma(q2[1], kb2[1], db2);
        da2 = pk_fma(q2[2], ka2[2], da2);  db2 = pk_fma(q2[2], kb2[2], db2);
        da2 = pk_fma(q2[3], ka2[3], da2);  db2 = pk_fma(q2[3], kb2[3], db2);
        float da = da2.x + da2.y;
        float db = db2.x + db2.y;
        da += __shfl_xor(da, 1);  db += __shfl_xor(db, 1);
        da += __shfl_xor(da, 2);  db += __shfl_xor(db, 2);
        da += __shfl_xor(da, 4);  db += __shfl_xor(db, 4);
        float pea = va ? __expf(da) : 0.f;
        float peb = vb ? __expf(db) : 0.f;
        l += pea + peb;
        float2v pa; pa.x = pea; pa.y = pea;
        float2v pb; pb.x = peb; pb.y = peb;
        #pragma unroll
        for (int i = 0; i < 4; i++) {
            o2[i] = pk_fma(pa, wa2[i], o2[i]);
            o2[i] = pk_fma(pb, wb2[i], o2[i]);
        }
        kua = kua_n; vua = vua_n; kub = kub_n; vub = vub_n;
    }
    #pragma unroll
    for (int offx = 16; offx <= 32; offx <<= 1) {
        l += __shfl_xor(l, offx);
        #pragma unroll
        for (int i = 0; i < 4; i++) {
            o2[i].x += __shfl_xor(o2[i].x, offx);
            o2[i].y += __shfl_xor(o2[i].y, offx);
        }
    }

    if (qtr == 0) {
        float inv = 1.f / (l + 1e-16f);
        float o[8] = {o2[0].x, o2[0].y, o2[1].x, o2[1].y,
                      o2[2].x, o2[2].y, o2[3].x, o2[3].y};
        float sv[8];
        {
            uint4 su = *reinterpret_cast<const uint4*>(row_qs + 128 + c0);
            sv[0] = bf2f(su.x & 0xffff); sv[1] = bf2f(su.x >> 16);
            sv[2] = bf2f(su.y & 0xffff); sv[3] = bf2f(su.y >> 16);
            sv[4] = bf2f(su.z & 0xffff); sv[5] = bf2f(su.z >> 16);
            sv[6] = bf2f(su.w & 0xffff); sv[7] = bf2f(su.w >> 16);
        }
        float gv[8], bv[8], mv[8], vr[8];
        *reinterpret_cast<float4*>(gv)     = *reinterpret_cast<const float4*>(bng + c0);
        *reinterpret_cast<float4*>(gv + 4) = *reinterpret_cast<const float4*>(bng + c0 + 4);
        *reinterpret_cast<float4*>(bv)     = *reinterpret_cast<const float4*>(bnb + c0);
        *reinterpret_cast<float4*>(bv + 4) = *reinterpret_cast<const float4*>(bnb + c0 + 4);
        *reinterpret_cast<float4*>(mv)     = *reinterpret_cast<const float4*>(bnm + c0);
        *reinterpret_cast<float4*>(mv + 4) = *reinterpret_cast<const float4*>(bnm + c0 + 4);
        *reinterpret_cast<float4*>(vr)     = *reinterpret_cast<const float4*>(bnv + c0);
        *reinterpret_cast<float4*>(vr + 4) = *reinterpret_cast<const float4*>(bnv + c0 + 4);
        uint_t hw[4];
        #pragma unroll
        for (int i = 0; i < 8; i++) {
            float val = fmaxf(o[i] * inv + sv[i], 0.f);
            val = (val - mv[i]) * rsqrtf(vr[i] + 1e-5f) * gv[i] + bv[i];
            val = fmaxf(val, 0.f);
            ushort_t hb = f2bf(val);
            if (i & 1) hw[i >> 1] |= (uint_t)hb << 16;
            else       hw[i >> 1] = hb;
        }
        int rt = n >> 4, mnode = n & 15;
        int kt = s16 >> 2, qd = s16 & 3;
        size_t fidx = (size_t)rt * 2048 + kt * 512 + (mnode + 16 * qd) * 8;
        uint4 hp; hp.x = hw[0]; hp.y = hw[1]; hp.z = hw[2]; hp.w = hw[3];
        *reinterpret_cast<uint4*>(h + fidx) = hp;
    }
}

// ---------- merged pool + final head (batch sorted -> per-graph ranges) -----
__global__ __launch_bounds__(256) void final_pool(
    const ushort_t* __restrict__ h, const int* __restrict__ gstart,
    const float* __restrict__ fusdoc, const float* __restrict__ Wfus,
    const float* __restrict__ Wtask, const float* __restrict__ btask,
    const float* __restrict__ Wtime, const float* __restrict__ btime,
    float* __restrict__ out) {
    __shared__ float lsum[16][136];
    __shared__ float gbuf[128], fbuf[128], red[256];
    int b = blockIdx.x, t = threadIdx.x;
    int r0 = gstart[b], r1 = gstart[b + 1];
    int o = t & 15, s = t >> 4;       // o: channel octet, s: node slot
    int kt = o >> 2, qd = o & 3;
    float f0 = 0, f1 = 0, f2 = 0, f3 = 0, f4 = 0, f5 = 0, f6 = 0, f7 = 0;
    for (int n = r0 + s; n < r1; n += 16) {
        int rt = n >> 4, mn = n & 15;
        uint4 d = *reinterpret_cast<const uint4*>(
            h + (size_t)rt * 2048 + kt * 512 + (mn + 16 * qd) * 8);
        f0 += bf2f(d.x & 0xffff); f1 += bf2f(d.x >> 16);
        f2 += bf2f(d.y & 0xffff); f3 += bf2f(d.y >> 16);
        f4 += bf2f(d.z & 0xffff); f5 += bf2f(d.z >> 16);
        f6 += bf2f(d.w & 0xffff); f7 += bf2f(d.w >> 16);
    }
    int c0 = kt * 32 + qd * 8;
    float* dst = &lsum[s][c0];
    dst[0] = f0; dst[1] = f1; dst[2] = f2; dst[3] = f3;
    dst[4] = f4; dst[5] = f5; dst[6] = f6; dst[7] = f7;
    __syncthreads();
    if (t < 128) {
        float a = 0.f;
        #pragma unroll
        for (int i = 0; i < 16; i++) a += lsum[i][t];
        gbuf[t] = a / fmaxf((float)(r1 - r0), 1.f);
    }
    __syncthreads();
    int c = t & 127, half = t >> 7;
    float f = (half == 0) ? fusdoc[b * 128 + c] : 0.f;
    int k0 = half * 64;
    #pragma unroll 8
    for (int k = 0; k < 64; k++)
        f += gbuf[k0 + k] * Wfus[(size_t)(k0 + k) * 128 + c];
    red[t] = f;
    __syncthreads();
    if (t < 128) fbuf[t] = fmaxf(red[t] + red[t + 128], 0.f);
    __syncthreads();
    if (t < 16) {
        float a = btask[t];
        #pragma unroll 8
        for (int k = 0; k < 128; k++) a += fbuf[k] * Wtask[k * 16 + t];
        out[b * 16 + t] = a;
    } else if (t == 16) {
        float a = btime[0];
        #pragma unroll 8
        for (int k = 0; k < 128; k++) a += fbuf[k] * Wtime[k];
        out[NGRAPH * 16 + b] = a;
    }
}

extern "C" void kernel_launch(void* const* d_in, const int* in_sizes, int n_in,
                              void* d_out, int out_size, void* d_ws, size_t ws_size,
                              hipStream_t stream) {
    (void)in_sizes; (void)n_in; (void)out_size; (void)ws_size;
    const float* x    = (const float*)d_in[0];
    const int*   ei   = (const int*)d_in[1];
    const int*   batch= (const int*)d_in[2];
    const float* ts   = (const float*)d_in[3];
    const float* doc  = (const float*)d_in[4];
    const float* Wq1  = (const float*)d_in[5];
    const float* bq1  = (const float*)d_in[6];
    const float* Wk1  = (const float*)d_in[7];
    const float* bk1  = (const float*)d_in[8];
    const float* Wv1  = (const float*)d_in[9];
    const float* bv1  = (const float*)d_in[10];
    const float* Ws1  = (const float*)d_in[11];
    const float* bs1  = (const float*)d_in[12];
    const float* Wq2  = (const float*)d_in[13];
    const float* bq2  = (const float*)d_in[14];
    const float* Wk2  = (const float*)d_in[15];
    const float* bk2  = (const float*)d_in[16];
    const float* Wv2  = (const float*)d_in[17];
    const float* bv2  = (const float*)d_in[18];
    const float* Ws2  = (const float*)d_in[19];
    const float* bs2  = (const float*)d_in[20];
    const float* bn1g = (const float*)d_in[21];
    const float* bn1b = (const float*)d_in[22];
    const float* bn1m = (const float*)d_in[23];
    const float* bn1v = (const float*)d_in[24];
    const float* bn2g = (const float*)d_in[25];
    const float* bn2b = (const float*)d_in[26];
    const float* bn2m = (const float*)d_in[27];
    const float* bn2v = (const float*)d_in[28];
    const float* Wdoc = (const float*)d_in[29];
    const float* bdoc = (const float*)d_in[30];
    const float* Wfus = (const float*)d_in[31];
    const float* bfus = (const float*)d_in[32];
    const float* Wtask= (const float*)d_in[33];
    const float* btask= (const float*)d_in[34];
    const float* Wtime= (const float*)d_in[35];
    const float* btime= (const float*)d_in[36];

    char* ws = (char*)d_ws;
    ushort_t* h      = (ushort_t*)(ws + 0);           // 12.8 MB
    ushort_t* qsb    = (ushort_t*)(ws + 12800000);    // 25.6 MB
    uchar_t*  kv8    = (uchar_t*)(ws + 38400000);     // 12.8 MB
    ushort_t* WF     = (ushort_t*)(ws + 51200000);    // 256 KB
    float*    biasc  = (float*)(ws + 51462144);       // 4 KB
    int*      gstart = (int*)(ws + 51466240);         // 260 B
    int*      off    = (int*)(ws + 51499264);         // 200004 B
    int*      bucketcur = (int*)(ws + 51699268);      // 784 B
    int*      arena  = (int*)(ws + 51700052);         // 196*8192*4 = 6.42 MB
    int*      csr    = (int*)(ws + 58122580);         // 3.2 MB
    float*    docemb = (float*)(ws + 61322580);       // 32 KB
    float*    fusdoc = (float*)(ws + 61355348);       // 32 KB

    float* out = (float*)d_out;

    hipMemsetAsync(bucketcur, 0, 784, stream);

    prep_edges<<<NBKT, 256, 0, stream>>>(ei, bucketcur, arena);
    prep_feat<<<NB_TEMP + NB_WS + NGRAPH + NB_GS, 256, 0, stream>>>(
        x, ts, h,
        Wq1, Wk1, Wv1, Ws1, Wq2, Wk2, Wv2, Ws2,
        bq1, bk1, bv1, bs1, bq2, bk2, bv2, bs2, WF, biasc,
        doc, Wdoc, bdoc, docemb, batch, gstart);
    passb_kernel<<<NBKT, 256, 0, stream>>>(off, arena, bucketcur, csr);

    const size_t WF_LAYER = 65536;  // shorts per layer

    // ---- layer 1 ----
    gemm1_kernel<<<NB_GEMM + NGRAPH, 256, 0, stream>>>(
        h, WF, biasc, qsb, kv8, docemb, Wfus, bfus, fusdoc);
    node_attn_bn<<<12500, 256, 0, stream>>>(off, csr, qsb, kv8, bn1g, bn1b, bn1m, bn1v, h);

    // ---- layer 2 ----
    gemm_qkvs<<<dim3(391, 4), 256, 0, stream>>>(h, WF + WF_LAYER, biasc + 512, qsb, kv8);
    node_attn_bn<<<12500, 256, 0, stream>>>(off, csr, qsb, kv8, bn2g, bn2b, bn2m, bn2v, h);

    // ---- merged pool + final head ----
    final_pool<<<NGRAPH, 256, 0, stream>>>(h, gstart, fusdoc, Wfus,
                                           Wtask, btask, Wtime, btime, out);
}

// Round 7
// 331.195 us; speedup vs baseline: 1.1304x; 1.0566x over previous
//
#include <hip/hip_runtime.h>

typedef unsigned short ushort_t;
typedef unsigned int uint_t;
typedef unsigned char uchar_t;
typedef unsigned long long ull_t;

#define N_NODES 50000
#define N_EDGES 800000
#define HID 128
#define NGRAPH 64
#define N_RT 3125     // row tiles of 16 nodes
#define NBKT 196      // coarse buckets of 256 nodes
#define CHUNK 4096    // edges per pass-A block
#define NB_TEMP 3125  // temporal blocks (256 thr x 8 elems, vectorized)
#define NB_WS 512     // wsplit blocks
#define NB_GS 196     // gstart scan blocks
#define NB_GEMM 1564  // 4*391
#define BCAP 6144     // passB LDS stage capacity (mean 4096 + 32 sigma)
#define BMAX 8192     // arena slot per bucket (mean + 64 sigma)

typedef __attribute__((ext_vector_type(8))) short short8;
typedef __attribute__((ext_vector_type(4))) float float4v;
typedef __attribute__((ext_vector_type(2))) float float2v;

// ---------- bf16 helpers ----------
__device__ __forceinline__ float bf2f(uint_t u) {
    union { uint_t i; float f; } v; v.i = u << 16; return v.f;
}
__device__ __forceinline__ ushort_t f2bf(float f) {
    union { float f; uint_t i; } v; v.f = f;
    uint_t r = v.i + 0x7FFFu + ((v.i >> 16) & 1u);
    return (ushort_t)(r >> 16);
}

// ---------- fp8 e4m3 helpers ----------
__device__ __forceinline__ void fp8x4_dec2(uint_t w, float2v* o) {
    o[0] = __builtin_amdgcn_cvt_pk_f32_fp8(w, false);
    o[1] = __builtin_amdgcn_cvt_pk_f32_fp8(w, true);
}

// ---------- packed-f32 VOP3P ----------
__device__ __forceinline__ float2v pk_mul(float2v a, float2v b) {
    float2v d;
    asm("v_pk_mul_f32 %0, %1, %2" : "=v"(d) : "v"(a), "v"(b));
    return d;
}
__device__ __forceinline__ float2v pk_fma(float2v a, float2v b, float2v c) {
    float2v d;
    asm("v_pk_fma_f32 %0, %1, %2, %3" : "=v"(d) : "v"(a), "v"(b), "v"(c));
    return d;
}

// ---------- prep mega-kernel: passA + temporal + wsplit + docemb + gstart ---
// Merged (R4 structure): phases run concurrently at block granularity.
__global__ __launch_bounds__(256) void prep_kernel(
    const int* __restrict__ ei,
    int* __restrict__ bucketcur, int* __restrict__ arena,
    const float* __restrict__ x, const float* __restrict__ ts,
    ushort_t* __restrict__ h,
    const float* __restrict__ Wq1, const float* __restrict__ Wk1,
    const float* __restrict__ Wv1, const float* __restrict__ Ws1,
    const float* __restrict__ Wq2, const float* __restrict__ Wk2,
    const float* __restrict__ Wv2, const float* __restrict__ Ws2,
    const float* __restrict__ bq1, const float* __restrict__ bk1,
    const float* __restrict__ bv1, const float* __restrict__ bs1,
    const float* __restrict__ bq2, const float* __restrict__ bk2,
    const float* __restrict__ bv2, const float* __restrict__ bs2,
    ushort_t* __restrict__ WF, float* __restrict__ bias_cat,
    const float* __restrict__ doc, const float* __restrict__ Wdoc,
    const float* __restrict__ bdoc, float* __restrict__ docemb,
    const int* __restrict__ batch, int* __restrict__ gstart) {
    __shared__ int hist[NBKT];
    __shared__ int lofs[NBKT];
    __shared__ int lcur[NBKT];
    __shared__ int gbase[NBKT];
    __shared__ int sbuf[256];
    __shared__ uint_t staging[CHUNK];
    __shared__ int tot_s;

    int blk = blockIdx.x;
    int t = threadIdx.x;

    if (blk < NBKT) {
        // ---------------- pass A ----------------
        if (t < NBKT) hist[t] = 0;
        __syncthreads();
        int e0 = blk * CHUNK;
        int srcs[16], dsts[16];
        #pragma unroll
        for (int i = 0; i < 16; i++) {
            int idx = e0 + i * 256 + t;
            bool v = idx < N_EDGES;
            srcs[i] = v ? ei[idx] : -1;
            dsts[i] = v ? ei[N_EDGES + idx] : -1;
            if (v) atomicAdd(&hist[dsts[i] >> 8], 1);
        }
        __syncthreads();
        int hv = (t < NBKT) ? hist[t] : 0;
        sbuf[t] = hv;
        __syncthreads();
        #pragma unroll
        for (int s = 1; s < 256; s <<= 1) {
            int add = (t >= s) ? sbuf[t - s] : 0;
            __syncthreads();
            sbuf[t] += add;
            __syncthreads();
        }
        if (t < NBKT) {
            lofs[t] = sbuf[t] - hv;
            lcur[t] = sbuf[t] - hv;
        }
        if (t == NBKT - 1) tot_s = sbuf[NBKT - 1];
        __syncthreads();
        #pragma unroll
        for (int i = 0; i < 16; i++) {
            if (srcs[i] >= 0) {
                int bkt = dsts[i] >> 8;
                int pos = atomicAdd(&lcur[bkt], 1);
                staging[pos] = ((uint_t)bkt << 24) | ((uint_t)(dsts[i] & 255) << 16)
                             | (uint_t)srcs[i];
            }
        }
        __syncthreads();
        if (t < NBKT) {
            int hcnt = hist[t];
            gbase[t] = t * BMAX + (hcnt ? atomicAdd(&bucketcur[t], hcnt) : 0);
        }
        __syncthreads();
        int tot = tot_s;
        for (int i = t; i < tot; i += 256) {
            uint_t e = staging[i];
            int bkt = e >> 24;
            arena[gbase[bkt] + (i - lofs[bkt])] = (int)(e & 0xFFFFFF);
        }
    } else if (blk < NBKT + NB_TEMP) {
        // ------- temporal, vectorized: 8 consecutive channels per thread ----
        // elem = tid2*8+j ; rt=tid2>>8, kt=(tid2>>6)&3, lane=tid2&63
        int tid2 = (blk - NBKT) * 256 + t;     // 0..799999
        int rt   = tid2 >> 8;
        int kt   = (tid2 >> 6) & 3;
        int lane = tid2 & 63;
        int n  = rt * 16 + (lane & 15);
        int c0 = kt * 32 + (lane >> 4) * 8;
        float tv = ts[n];
        const float coef = -0.07195570687f;    // -ln(10000)/128
        float4 x0 = *reinterpret_cast<const float4*>(x + (size_t)n * 128 + c0);
        float4 x1 = *reinterpret_cast<const float4*>(x + (size_t)n * 128 + c0 + 4);
        float xv[8] = {x0.x, x0.y, x0.z, x0.w, x1.x, x1.y, x1.z, x1.w};
        uint_t hw[4];
        #pragma unroll
        for (int i = 0; i < 4; i++) {
            float ang = tv * __expf((float)(c0 + 2 * i) * coef);
            float sn, cs;
            __sincosf(ang, &sn, &cs);
            float v0 = xv[2 * i] + sn;
            float v1 = xv[2 * i + 1] + cs;
            uint_t pk;
            asm("v_cvt_pk_bf16_f32 %0, %1, %2" : "=v"(pk) : "v"(v0), "v"(v1));
            hw[i] = pk;
        }
        uint4 hp; hp.x = hw[0]; hp.y = hw[1]; hp.z = hw[2]; hp.w = hw[3];
        *reinterpret_cast<uint4*>(h + (size_t)tid2 * 8) = hp;
    } else if (blk < NBKT + NB_TEMP + NB_WS) {
        // ---------------- wsplit (Q weights+bias pre-scaled by 1/8) --------
        int tid = (blk - NBKT - NB_TEMP) * 256 + t;  // 0..131071
        int j    = tid & 7;
        int lane = (tid >> 3) & 63;
        int kt   = (tid >> 9) & 3;
        int cgy  = (tid >> 11) & 31;
        int L    = tid >> 16;
        int col = cgy * 16 + (lane & 15);
        int k   = kt * 32 + (lane >> 4) * 8 + j;
        int mat = col >> 7, c = col & 127;
        const float* W = (L == 0)
            ? ((mat == 0) ? Wq1 : (mat == 1) ? Wk1 : (mat == 2) ? Wv1 : Ws1)
            : ((mat == 0) ? Wq2 : (mat == 1) ? Wk2 : (mat == 2) ? Wv2 : Ws2);
        size_t base = (size_t)L * 65536 + (size_t)cgy * 2048 + (size_t)kt * 512;
        float wv = W[k * 128 + c];
        if (mat == 0) wv *= 0.125f;           // fold q-scale (exact in bf16)
        WF[base + lane * 8 + j] = f2bf(wv);
        if (kt == 0 && (lane >> 4) == 0 && j == 0) {
            const float* b = (L == 0)
                ? ((mat == 0) ? bq1 : (mat == 1) ? bk1 : (mat == 2) ? bv1 : bs1)
                : ((mat == 0) ? bq2 : (mat == 1) ? bk2 : (mat == 2) ? bv2 : bs2);
            float bb = b[c];
            if (mat == 0) bb *= 0.125f;
            bias_cat[L * 512 + col] = bb;
        }
    } else if (blk < NBKT + NB_TEMP + NB_WS + NGRAPH) {
        // ---------------- docemb ----------------
        int b = blk - NBKT - NB_TEMP - NB_WS;   // 0..63
        int c = t & 127, half = t >> 7;
        float* red = (float*)staging;           // reuse LDS
        float acc = (half == 0) ? bdoc[c] : 0.f;
        int k0 = half * 256;
        #pragma unroll 8
        for (int k = 0; k < 256; k++)
            acc += doc[b * 512 + k0 + k] * Wdoc[(size_t)(k0 + k) * 128 + c];
        red[t] = acc;
        __syncthreads();
        if (t < 128) docemb[b * 128 + c] = fmaxf(red[t] + red[t + 128], 0.f);
    } else {
        // ---------------- gstart scan (batch is sorted) ----------------
        int gblk = blk - NBKT - NB_TEMP - NB_WS - NGRAPH;  // 0..195
        int i = gblk * 256 + t;
        if (i < N_NODES) {
            int bi = batch[i];
            int bp = (i == 0) ? -1 : batch[i - 1];
            if (bi != bp) {
                for (int g = bp + 1; g <= bi; g++) gstart[g] = i;
            }
            if (i == N_NODES - 1) {
                for (int g = bi + 1; g <= NGRAPH; g++) gstart[g] = N_NODES;
            }
        }
    }
}

// ---------- shared gemm body: swapped-operand MFMA, vectorized epilogue -----
__device__ __forceinline__ void gemm_body(
    int rp, int cg0, int lane,
    const ushort_t* __restrict__ hf, const ushort_t* __restrict__ WF,
    const float* __restrict__ bias_cat,
    ushort_t* __restrict__ qsb, uchar_t* __restrict__ kv8) {
    int rt0 = rp * 2;
    if (rt0 >= N_RT) return;
    int rt1 = rt0 + 1;
    int rt1c = (rt1 < N_RT) ? rt1 : rt0;

    short8 a0[4], a1[4];
    {
        const ushort_t* b0 = hf + (size_t)rt0 * 2048 + lane * 8;
        const ushort_t* b1 = hf + (size_t)rt1c * 2048 + lane * 8;
        #pragma unroll
        for (int kt = 0; kt < 4; kt++) {
            a0[kt] = *reinterpret_cast<const short8*>(b0 + kt * 512);
            a1[kt] = *reinterpret_cast<const short8*>(b1 + kt * 512);
        }
    }

    const ushort_t* wfl = WF + (size_t)cg0 * 2048 + lane * 8;
    short8 bh[4];
    #pragma unroll
    for (int kt = 0; kt < 4; kt++)
        bh[kt] = *reinterpret_cast<const short8*>(wfl + kt * 512);

    int m = lane & 15;        // node within tile (C col after swap)
    int quad = lane >> 4;     // channel quad   (C row group after swap)
    size_t node0 = (size_t)rt0 * 16 + m;
    size_t node1 = (size_t)rt1 * 16 + m;

    #pragma unroll 2
    for (int cg = 0; cg < 8; cg++) {
        short8 bn[4];
        if (cg < 7) {
            const ushort_t* fpn = wfl + (size_t)(cg + 1) * 2048;
            #pragma unroll
            for (int kt = 0; kt < 4; kt++)
                bn[kt] = *reinterpret_cast<const short8*>(fpn + kt * 512);
        }
        float4v acc0 = {0.f, 0.f, 0.f, 0.f};
        float4v acc1 = {0.f, 0.f, 0.f, 0.f};
        #pragma unroll
        for (int kt = 0; kt < 4; kt++) {
            acc0 = __builtin_amdgcn_mfma_f32_16x16x32_bf16(bh[kt], a0[kt], acc0, 0, 0, 0);
            acc1 = __builtin_amdgcn_mfma_f32_16x16x32_bf16(bh[kt], a1[kt], acc1, 0, 0, 0);
        }
        int col0 = (cg0 + cg) * 16;
        int chq = col0 + quad * 4;          // global column of acc[0]
        float4 b4 = *reinterpret_cast<const float4*>(bias_cat + chq);
        int mat = col0 >> 7;
        {
            float v0 = acc0[0] + b4.x, v1 = acc0[1] + b4.y;
            float v2 = acc0[2] + b4.z, v3 = acc0[3] + b4.w;
            if (mat == 0 || mat == 3) {
                uint_t lo, hi;
                asm("v_cvt_pk_bf16_f32 %0, %1, %2" : "=v"(lo) : "v"(v0), "v"(v1));
                asm("v_cvt_pk_bf16_f32 %0, %1, %2" : "=v"(hi) : "v"(v2), "v"(v3));
                int cq = (mat == 0) ? chq : (chq - 256);   // S -> [128,256)
                uint2 pk; pk.x = lo; pk.y = hi;
                *reinterpret_cast<uint2*>(qsb + node0 * 256 + cq) = pk;
            } else {
                int w = __builtin_amdgcn_cvt_pk_fp8_f32(v0, v1, 0, false);
                w = __builtin_amdgcn_cvt_pk_fp8_f32(v2, v3, w, true);
                *reinterpret_cast<uint_t*>(kv8 + node0 * 256 + (chq - 128)) = (uint_t)w;
            }
        }
        if (rt1 < N_RT) {
            float v0 = acc1[0] + b4.x, v1 = acc1[1] + b4.y;
            float v2 = acc1[2] + b4.z, v3 = acc1[3] + b4.w;
            if (mat == 0 || mat == 3) {
                uint_t lo, hi;
                asm("v_cvt_pk_bf16_f32 %0, %1, %2" : "=v"(lo) : "v"(v0), "v"(v1));
                asm("v_cvt_pk_bf16_f32 %0, %1, %2" : "=v"(hi) : "v"(v2), "v"(v3));
                int cq = (mat == 0) ? chq : (chq - 256);
                uint2 pk; pk.x = lo; pk.y = hi;
                *reinterpret_cast<uint2*>(qsb + node1 * 256 + cq) = pk;
            } else {
                int w = __builtin_amdgcn_cvt_pk_fp8_f32(v0, v1, 0, false);
                w = __builtin_amdgcn_cvt_pk_fp8_f32(v2, v3, w, true);
                *reinterpret_cast<uint_t*>(kv8 + node1 * 256 + (chq - 128)) = (uint_t)w;
            }
        }
        #pragma unroll
        for (int kt = 0; kt < 4; kt++) bh[kt] = bn[kt];
    }
}

// ---------- fused: passB (off+csr build) + gemm L1 + fusdoc -----------------
__global__ __launch_bounds__(256) void g1_kernel(
    int* __restrict__ off, const int* __restrict__ arena,
    const int* __restrict__ bucketcur, int* __restrict__ csr,
    const ushort_t* __restrict__ hf, const ushort_t* __restrict__ WF,
    const float* __restrict__ bias_cat,
    ushort_t* __restrict__ qsb, uchar_t* __restrict__ kv8,
    const float* __restrict__ docemb, const float* __restrict__ Wfus,
    const float* __restrict__ bfus, float* __restrict__ fusdoc) {
    __shared__ uint_t smem[BCAP + 1024];
    __shared__ int bbase_s;
    int blk = blockIdx.x;
    int t = threadIdx.x;
    if (blk < NBKT) {
        // ---- passB: derive off[] + exact csr from arena bucket ----
        uint_t* stage = smem;
        int* lcnt = (int*)(smem + BCAP);
        int* exc  = (int*)(smem + BCAP + 256);
        int* lcur = (int*)(smem + BCAP + 512);
        int* sb   = (int*)(smem + BCAP + 768);
        int bc = (t < NBKT) ? bucketcur[t] : 0;
        sb[t] = bc;
        __syncthreads();
        #pragma unroll
        for (int s = 1; s < 256; s <<= 1) {
            int a = (t >= s) ? sb[t - s] : 0;
            __syncthreads();
            sb[t] += a;
            __syncthreads();
        }
        if (t == 0) bbase_s = (blk == 0) ? 0 : sb[blk - 1];
        lcnt[t] = 0; lcur[t] = 0;
        __syncthreads();
        int bbase = bbase_s;
        int size = bucketcur[blk];
        int abase = blk * BMAX;
        int lim = (size < BCAP) ? size : BCAP;
        for (int i = t; i < lim; i += 256) stage[i] = (uint_t)arena[abase + i];
        __syncthreads();
        for (int i = t; i < size; i += 256) {
            uint_t e = (i < BCAP) ? stage[i] : (uint_t)arena[abase + i];
            atomicAdd(&lcnt[(e >> 16) & 255], 1);
        }
        __syncthreads();
        int v = lcnt[t];
        sb[t] = v;
        __syncthreads();
        #pragma unroll
        for (int s = 1; s < 256; s <<= 1) {
            int a = (t >= s) ? sb[t - s] : 0;
            __syncthreads();
            sb[t] += a;
            __syncthreads();
        }
        exc[t] = sb[t] - v;
        int n0 = blk * 256;
        if (n0 + t < N_NODES) off[n0 + t] = bbase + sb[t] - v;
        if (blk == NBKT - 1 && t == 0) off[N_NODES] = N_EDGES;
        __syncthreads();
        for (int i = t; i < size; i += 256) {
            uint_t e = (i < BCAP) ? stage[i] : (uint_t)arena[abase + i];
            int dlow = (e >> 16) & 255;
            int src = (int)(e & 0xFFFF);
            int pos = exc[dlow] + atomicAdd(&lcur[dlow], 1);
            csr[bbase + pos] = src << 8;   // byte offset into kv8
        }
    } else if (blk < NBKT + NB_GEMM) {
        int blk2 = blk - NBKT;           // 0..1563
        int y = blk2 / 391, bx = blk2 % 391;
        int wave = t >> 6, lane = t & 63;
        gemm_body(bx * 4 + wave, y * 8, lane, hf, WF, bias_cat, qsb, kv8);
    } else {
        // ---- fusdoc[b][c] = bfus[c] + docemb[b] @ Wfus[128:256] ----
        int b = blk - NBKT - NB_GEMM;    // 0..63
        int c = t & 127, half = t >> 7;
        float* de = (float*)smem;
        float* red = (float*)smem + 128;
        if (t < 128) de[t] = docemb[b * 128 + t];
        __syncthreads();
        float acc = (half == 0) ? bfus[c] : 0.f;
        int k0 = half * 64;
        #pragma unroll 8
        for (int k = 0; k < 64; k++)
            acc += de[k0 + k] * Wfus[(size_t)(128 + k0 + k) * 128 + c];
        red[t] = acc;
        __syncthreads();
        if (t < 128) fusdoc[b * 128 + c] = red[t] + red[t + 128];
    }
}

// ---------- plain gemm (layer 2) ----------
__global__ __launch_bounds__(256) void gemm_qkvs(
    const ushort_t* __restrict__ hf,
    const ushort_t* __restrict__ WF,
    const float* __restrict__ bias_cat,
    ushort_t* __restrict__ qsb, uchar_t* __restrict__ kv8) {
    int t = threadIdx.x;
    int wave = t >> 6, lane = t & 63;
    gemm_body(blockIdx.x * 4 + wave, blockIdx.y * 8, lane,
              hf, WF, bias_cat, qsb, kv8);
}

// ---------- fused per-node attention + skip + BN + relu -> h (frag-major) ----
// csr_src holds src*256 (byte offset). 16 lanes/edge, 8 edges/iter, K/V data
// prefetched one iteration ahead, packed-f32 math. (R4-proven version.)
__global__ __launch_bounds__(256) void node_attn_bn(
    const int* __restrict__ off, const int* __restrict__ csr_src,
    const ushort_t* __restrict__ qsb, const uchar_t* __restrict__ kv8,
    const float* __restrict__ bng, const float* __restrict__ bnb,
    const float* __restrict__ bnm, const float* __restrict__ bnv,
    ushort_t* __restrict__ h) {
    int wave = threadIdx.x >> 6;
    int n = blockIdx.x * 4 + wave;
    if (n >= N_NODES) return;
    int lane = threadIdx.x & 63;
    int qtr = lane >> 4, s16 = lane & 15;
    int c0 = s16 * 8;

    const ushort_t* row_qs = qsb + (size_t)n * 256;
    float2v q2[4];
    {
        uint4 qu = *reinterpret_cast<const uint4*>(row_qs + c0);
        q2[0].x = bf2f(qu.x & 0xffff); q2[0].y = bf2f(qu.x >> 16);
        q2[1].x = bf2f(qu.y & 0xffff); q2[1].y = bf2f(qu.y >> 16);
        q2[2].x = bf2f(qu.z & 0xffff); q2[2].y = bf2f(qu.z >> 16);
        q2[3].x = bf2f(qu.w & 0xffff); q2[3].y = bf2f(qu.w >> 16);
    }

    int e0 = off[n], e1 = off[n + 1];
    float l = 0.f;
    float2v o2[4];
    o2[0] = (float2v){0.f, 0.f}; o2[1] = (float2v){0.f, 0.f};
    o2[2] = (float2v){0.f, 0.f}; o2[3] = (float2v){0.f, 0.f};

    int src_a = (e0 + qtr < e1) ? csr_src[e0 + qtr] : 0;
    int src_b = (e0 + 4 + qtr < e1) ? csr_src[e0 + 4 + qtr] : 0;
    uint2 kua, vua, kub, vub;
    {
        const uchar_t* kpa = kv8 + (uint_t)src_a;
        const uchar_t* kpb = kv8 + (uint_t)src_b;
        kua = *reinterpret_cast<const uint2*>(kpa + c0);
        vua = *reinterpret_cast<const uint2*>(kpa + 128 + c0);
        kub = *reinterpret_cast<const uint2*>(kpb + c0);
        vub = *reinterpret_cast<const uint2*>(kpb + 128 + c0);
    }

    for (int p = e0; p < e1; p += 8) {
        bool va = (p + qtr) < e1, vb = (p + 4 + qtr) < e1;
        int na = p + 8 + qtr, nb = p + 12 + qtr;
        int nsa = (na < e1) ? csr_src[na] : 0;
        int nsb = (nb < e1) ? csr_src[nb] : 0;
        const uchar_t* kpa_n = kv8 + (uint_t)nsa;
        const uchar_t* kpb_n = kv8 + (uint_t)nsb;
        uint2 kua_n = *reinterpret_cast<const uint2*>(kpa_n + c0);
        uint2 vua_n = *reinterpret_cast<const uint2*>(kpa_n + 128 + c0);
        uint2 kub_n = *reinterpret_cast<const uint2*>(kpb_n + c0);
        uint2 vub_n = *reinterpret_cast<const uint2*>(kpb_n + 128 + c0);

        float2v ka2[4], wa2[4], kb2[4], wb2[4];
        fp8x4_dec2(kua.x, ka2);  fp8x4_dec2(kua.y, ka2 + 2);
        fp8x4_dec2(kub.x, kb2);  fp8x4_dec2(kub.y, kb2 + 2);
        fp8x4_dec2(vua.x, wa2);  fp8x4_dec2(vua.y, wa2 + 2);
        fp8x4_dec2(vub.x, wb2);  fp8x4_dec2(vub.y, wb2 + 2);

        float2v da2 = pk_mul(q2[0], ka2[0]);
        float2v db2 = pk_mul(q2[0], kb2[0]);
        da2 = pk_fma(q2[1], ka2[1], da2);  db2 = pk_fma(q2[1], kb2[1], db2);
        da2 = pk_fma(q2[2], ka2[2], da2);  db2 = pk_fma(q2[2], kb2[2], db2);
        da2 = pk_fma(q2[3], ka2[3], da2);  db2 = pk_fma(q2[3], kb2[3], db2);
        float da = da2.x + da2.y;
        float db = db2.x + db2.y;
        da += __shfl_xor(da, 1);  db += __shfl_xor(db, 1);
        da += __shfl_xor(da, 2);  db += __shfl_xor(db, 2);
        da += __shfl_xor(da, 4);  db += __shfl_xor(db, 4);
        float pea = va ? __expf(da) : 0.f;
        float peb = vb ? __expf(db) : 0.f;
        l += pea + peb;
        float2v pa; pa.x = pea; pa.y = pea;
        float2v pb; pb.x = peb; pb.y = peb;
        #pragma unroll
        for (int i = 0; i < 4; i++) {
            o2[i] = pk_fma(pa, wa2[i], o2[i]);
            o2[i] = pk_fma(pb, wb2[i], o2[i]);
        }
        kua = kua_n; vua = vua_n; kub = kub_n; vub = vub_n;
    }
    #pragma unroll
    for (int offx = 16; offx <= 32; offx <<= 1) {
        l += __shfl_xor(l, offx);
        #pragma unroll
        for (int i = 0; i < 4; i++) {
            o2[i].x += __shfl_xor(o2[i].x, offx);
            o2[i].y += __shfl_xor(o2[i].y, offx);
        }
    }

    if (qtr == 0) {
        float inv = 1.f / (l + 1e-16f);
        float o[8] = {o2[0].x, o2[0].y, o2[1].x, o2[1].y,
                      o2[2].x, o2[2].y, o2[3].x, o2[3].y};
        float sv[8];
        {
            uint4 su = *reinterpret_cast<const uint4*>(row_qs + 128 + c0);
            sv[0] = bf2f(su.x & 0xffff); sv[1] = bf2f(su.x >> 16);
            sv[2] = bf2f(su.y & 0xffff); sv[3] = bf2f(su.y >> 16);
            sv[4] = bf2f(su.z & 0xffff); sv[5] = bf2f(su.z >> 16);
            sv[6] = bf2f(su.w & 0xffff); sv[7] = bf2f(su.w >> 16);
        }
        float gv[8], bv[8], mv[8], vr[8];
        *reinterpret_cast<float4*>(gv)     = *reinterpret_cast<const float4*>(bng + c0);
        *reinterpret_cast<float4*>(gv + 4) = *reinterpret_cast<const float4*>(bng + c0 + 4);
        *reinterpret_cast<float4*>(bv)     = *reinterpret_cast<const float4*>(bnb + c0);
        *reinterpret_cast<float4*>(bv + 4) = *reinterpret_cast<const float4*>(bnb + c0 + 4);
        *reinterpret_cast<float4*>(mv)     = *reinterpret_cast<const float4*>(bnm + c0);
        *reinterpret_cast<float4*>(mv + 4) = *reinterpret_cast<const float4*>(bnm + c0 + 4);
        *reinterpret_cast<float4*>(vr)     = *reinterpret_cast<const float4*>(bnv + c0);
        *reinterpret_cast<float4*>(vr + 4) = *reinterpret_cast<const float4*>(bnv + c0 + 4);
        uint_t hw[4];
        #pragma unroll
        for (int i = 0; i < 8; i++) {
            float val = fmaxf(o[i] * inv + sv[i], 0.f);
            val = (val - mv[i]) * rsqrtf(vr[i] + 1e-5f) * gv[i] + bv[i];
            val = fmaxf(val, 0.f);
            ushort_t hb = f2bf(val);
            if (i & 1) hw[i >> 1] |= (uint_t)hb << 16;
            else       hw[i >> 1] = hb;
        }
        int rt = n >> 4, mnode = n & 15;
        int kt = s16 >> 2, qd = s16 & 3;
        size_t fidx = (size_t)rt * 2048 + kt * 512 + (mnode + 16 * qd) * 8;
        uint4 hp; hp.x = hw[0]; hp.y = hw[1]; hp.z = hw[2]; hp.w = hw[3];
        *reinterpret_cast<uint4*>(h + fidx) = hp;
    }
}

// ---------- merged pool + final head (batch sorted -> per-graph ranges) -----
__global__ __launch_bounds__(256) void final_pool(
    const ushort_t* __restrict__ h, const int* __restrict__ gstart,
    const float* __restrict__ fusdoc, const float* __restrict__ Wfus,
    const float* __restrict__ Wtask, const float* __restrict__ btask,
    const float* __restrict__ Wtime, const float* __restrict__ btime,
    float* __restrict__ out) {
    __shared__ float lsum[16][136];
    __shared__ float gbuf[128], fbuf[128], red[256];
    int b = blockIdx.x, t = threadIdx.x;
    int r0 = gstart[b], r1 = gstart[b + 1];
    int o = t & 15, s = t >> 4;       // o: channel octet, s: node slot
    int kt = o >> 2, qd = o & 3;
    float f0 = 0, f1 = 0, f2 = 0, f3 = 0, f4 = 0, f5 = 0, f6 = 0, f7 = 0;
    for (int n = r0 + s; n < r1; n += 16) {
        int rt = n >> 4, mn = n & 15;
        uint4 d = *reinterpret_cast<const uint4*>(
            h + (size_t)rt * 2048 + kt * 512 + (mn + 16 * qd) * 8);
        f0 += bf2f(d.x & 0xffff); f1 += bf2f(d.x >> 16);
        f2 += bf2f(d.y & 0xffff); f3 += bf2f(d.y >> 16);
        f4 += bf2f(d.z & 0xffff); f5 += bf2f(d.z >> 16);
        f6 += bf2f(d.w & 0xffff); f7 += bf2f(d.w >> 16);
    }
    int c0 = kt * 32 + qd * 8;
    float* dst = &lsum[s][c0];
    dst[0] = f0; dst[1] = f1; dst[2] = f2; dst[3] = f3;
    dst[4] = f4; dst[5] = f5; dst[6] = f6; dst[7] = f7;
    __syncthreads();
    if (t < 128) {
        float a = 0.f;
        #pragma unroll
        for (int i = 0; i < 16; i++) a += lsum[i][t];
        gbuf[t] = a / fmaxf((float)(r1 - r0), 1.f);
    }
    __syncthreads();
    int c = t & 127, half = t >> 7;
    float f = (half == 0) ? fusdoc[b * 128 + c] : 0.f;
    int k0 = half * 64;
    #pragma unroll 8
    for (int k = 0; k < 64; k++)
        f += gbuf[k0 + k] * Wfus[(size_t)(k0 + k) * 128 + c];
    red[t] = f;
    __syncthreads();
    if (t < 128) fbuf[t] = fmaxf(red[t] + red[t + 128], 0.f);
    __syncthreads();
    if (t < 16) {
        float a = btask[t];
        #pragma unroll 8
        for (int k = 0; k < 128; k++) a += fbuf[k] * Wtask[k * 16 + t];
        out[b * 16 + t] = a;
    } else if (t == 16) {
        float a = btime[0];
        #pragma unroll 8
        for (int k = 0; k < 128; k++) a += fbuf[k] * Wtime[k];
        out[NGRAPH * 16 + b] = a;
    }
}

extern "C" void kernel_launch(void* const* d_in, const int* in_sizes, int n_in,
                              void* d_out, int out_size, void* d_ws, size_t ws_size,
                              hipStream_t stream) {
    (void)in_sizes; (void)n_in; (void)out_size; (void)ws_size;
    const float* x    = (const float*)d_in[0];
    const int*   ei   = (const int*)d_in[1];
    const int*   batch= (const int*)d_in[2];
    const float* ts   = (const float*)d_in[3];
    const float* doc  = (const float*)d_in[4];
    const float* Wq1  = (const float*)d_in[5];
    const float* bq1  = (const float*)d_in[6];
    const float* Wk1  = (const float*)d_in[7];
    const float* bk1  = (const float*)d_in[8];
    const float* Wv1  = (const float*)d_in[9];
    const float* bv1  = (const float*)d_in[10];
    const float* Ws1  = (const float*)d_in[11];
    const float* bs1  = (const float*)d_in[12];
    const float* Wq2  = (const float*)d_in[13];
    const float* bq2  = (const float*)d_in[14];
    const float* Wk2  = (const float*)d_in[15];
    const float* bk2  = (const float*)d_in[16];
    const float* Wv2  = (const float*)d_in[17];
    const float* bv2  = (const float*)d_in[18];
    const float* Ws2  = (const float*)d_in[19];
    const float* bs2  = (const float*)d_in[20];
    const float* bn1g = (const float*)d_in[21];
    const float* bn1b = (const float*)d_in[22];
    const float* bn1m = (const float*)d_in[23];
    const float* bn1v = (const float*)d_in[24];
    const float* bn2g = (const float*)d_in[25];
    const float* bn2b = (const float*)d_in[26];
    const float* bn2m = (const float*)d_in[27];
    const float* bn2v = (const float*)d_in[28];
    const float* Wdoc = (const float*)d_in[29];
    const float* bdoc = (const float*)d_in[30];
    const float* Wfus = (const float*)d_in[31];
    const float* bfus = (const float*)d_in[32];
    const float* Wtask= (const float*)d_in[33];
    const float* btask= (const float*)d_in[34];
    const float* Wtime= (const float*)d_in[35];
    const float* btime= (const float*)d_in[36];

    char* ws = (char*)d_ws;
    ushort_t* h      = (ushort_t*)(ws + 0);           // 12.8 MB
    ushort_t* qsb    = (ushort_t*)(ws + 12800000);    // 25.6 MB
    uchar_t*  kv8    = (uchar_t*)(ws + 38400000);     // 12.8 MB
    ushort_t* WF     = (ushort_t*)(ws + 51200000);    // 256 KB
    float*    biasc  = (float*)(ws + 51462144);       // 4 KB
    int*      gstart = (int*)(ws + 51466240);         // 260 B
    int*      off    = (int*)(ws + 51499264);         // 200004 B
    int*      bucketcur = (int*)(ws + 51699268);      // 784 B
    int*      arena  = (int*)(ws + 51700052);         // 196*8192*4 = 6.42 MB
    int*      csr    = (int*)(ws + 58122580);         // 3.2 MB
    float*    docemb = (float*)(ws + 61322580);       // 32 KB
    float*    fusdoc = (float*)(ws + 61355348);       // 32 KB

    float* out = (float*)d_out;

    hipMemsetAsync(bucketcur, 0, 784, stream);

    prep_kernel<<<NBKT + NB_TEMP + NB_WS + NGRAPH + NB_GS, 256, 0, stream>>>(
        ei, bucketcur, arena, x, ts, h,
        Wq1, Wk1, Wv1, Ws1, Wq2, Wk2, Wv2, Ws2,
        bq1, bk1, bv1, bs1, bq2, bk2, bv2, bs2, WF, biasc,
        doc, Wdoc, bdoc, docemb, batch, gstart);

    const size_t WF_LAYER = 65536;  // shorts per layer

    // ---- layer 1 (gemm fused with passB(off+csr) + fusdoc) ----
    g1_kernel<<<NBKT + NB_GEMM + NGRAPH, 256, 0, stream>>>(
        off, arena, bucketcur, csr, h, WF, biasc, qsb, kv8,
        docemb, Wfus, bfus, fusdoc);
    node_attn_bn<<<12500, 256, 0, stream>>>(off, csr, qsb, kv8, bn1g, bn1b, bn1m, bn1v, h);

    // ---- layer 2 ----
    gemm_qkvs<<<dim3(391, 4), 256, 0, stream>>>(h, WF + WF_LAYER, biasc + 512, qsb, kv8);
    node_attn_bn<<<12500, 256, 0, stream>>>(off, csr, qsb, kv8, bn2g, bn2b, bn2m, bn2v, h);

    // ---- merged pool + final head ----
    final_pool<<<NGRAPH, 256, 0, stream>>>(h, gstart, fusdoc, Wfus,
                                           Wtask, btask, Wtime, btime, out);
}

// Round 8
// 327.257 us; speedup vs baseline: 1.1440x; 1.0120x over previous
//
#include <hip/hip_runtime.h>

typedef unsigned short ushort_t;
typedef unsigned int uint_t;
typedef unsigned char uchar_t;
typedef unsigned long long ull_t;

#define N_NODES 50000
#define N_EDGES 800000
#define HID 128
#define NGRAPH 64
#define N_RT 3125     // row tiles of 16 nodes
#define NBKT 196      // coarse buckets of 256 nodes
#define CHUNK 4096    // edges per pass-A block
#define NB_TEMP 3125  // temporal blocks (256 thr x 8 elems, vectorized)
#define NB_WS 512     // wsplit blocks
#define NB_GS 196     // gstart scan blocks
#define NB_GEMM 782   // 2*391: y in {0,1}, 16 col-groups per wave
#define BCAP 6144     // passB LDS stage capacity (mean 4096 + 32 sigma)
#define BMAX 8192     // arena slot per bucket (mean + 64 sigma)

typedef __attribute__((ext_vector_type(8))) short short8;
typedef __attribute__((ext_vector_type(4))) float float4v;
typedef __attribute__((ext_vector_type(2))) float float2v;

// ---------- bf16 helpers ----------
__device__ __forceinline__ float bf2f(uint_t u) {
    union { uint_t i; float f; } v; v.i = u << 16; return v.f;
}
__device__ __forceinline__ ushort_t f2bf(float f) {
    union { float f; uint_t i; } v; v.f = f;
    uint_t r = v.i + 0x7FFFu + ((v.i >> 16) & 1u);
    return (ushort_t)(r >> 16);
}

// ---------- fp8 e4m3 helpers ----------
__device__ __forceinline__ void fp8x4_dec2(uint_t w, float2v* o) {
    o[0] = __builtin_amdgcn_cvt_pk_f32_fp8(w, false);
    o[1] = __builtin_amdgcn_cvt_pk_f32_fp8(w, true);
}

// ---------- packed-f32 VOP3P ----------
__device__ __forceinline__ float2v pk_mul(float2v a, float2v b) {
    float2v d;
    asm("v_pk_mul_f32 %0, %1, %2" : "=v"(d) : "v"(a), "v"(b));
    return d;
}
__device__ __forceinline__ float2v pk_fma(float2v a, float2v b, float2v c) {
    float2v d;
    asm("v_pk_fma_f32 %0, %1, %2, %3" : "=v"(d) : "v"(a), "v"(b), "v"(c));
    return d;
}

// ---------- prep mega-kernel: passA + temporal + wsplit + docemb + gstart ---
__global__ __launch_bounds__(256) void prep_kernel(
    const int* __restrict__ ei,
    int* __restrict__ bucketcur, int* __restrict__ arena,
    const float* __restrict__ x, const float* __restrict__ ts,
    ushort_t* __restrict__ h,
    const float* __restrict__ Wq1, const float* __restrict__ Wk1,
    const float* __restrict__ Wv1, const float* __restrict__ Ws1,
    const float* __restrict__ Wq2, const float* __restrict__ Wk2,
    const float* __restrict__ Wv2, const float* __restrict__ Ws2,
    const float* __restrict__ bq1, const float* __restrict__ bk1,
    const float* __restrict__ bv1, const float* __restrict__ bs1,
    const float* __restrict__ bq2, const float* __restrict__ bk2,
    const float* __restrict__ bv2, const float* __restrict__ bs2,
    ushort_t* __restrict__ WF, float* __restrict__ bias_cat,
    const float* __restrict__ doc, const float* __restrict__ Wdoc,
    const float* __restrict__ bdoc, float* __restrict__ docemb,
    const int* __restrict__ batch, int* __restrict__ gstart) {
    __shared__ int hist[NBKT];
    __shared__ int lofs[NBKT];
    __shared__ int lcur[NBKT];
    __shared__ int gbase[NBKT];
    __shared__ int sbuf[256];
    __shared__ uint_t staging[CHUNK];
    __shared__ int tot_s;

    int blk = blockIdx.x;
    int t = threadIdx.x;

    if (blk < NBKT) {
        // ---------------- pass A ----------------
        if (t < NBKT) hist[t] = 0;
        __syncthreads();
        int e0 = blk * CHUNK;
        int srcs[16], dsts[16];
        #pragma unroll
        for (int i = 0; i < 16; i++) {
            int idx = e0 + i * 256 + t;
            bool v = idx < N_EDGES;
            srcs[i] = v ? ei[idx] : -1;
            dsts[i] = v ? ei[N_EDGES + idx] : -1;
            if (v) atomicAdd(&hist[dsts[i] >> 8], 1);
        }
        __syncthreads();
        int hv = (t < NBKT) ? hist[t] : 0;
        sbuf[t] = hv;
        __syncthreads();
        #pragma unroll
        for (int s = 1; s < 256; s <<= 1) {
            int add = (t >= s) ? sbuf[t - s] : 0;
            __syncthreads();
            sbuf[t] += add;
            __syncthreads();
        }
        if (t < NBKT) {
            lofs[t] = sbuf[t] - hv;
            lcur[t] = sbuf[t] - hv;
        }
        if (t == NBKT - 1) tot_s = sbuf[NBKT - 1];
        __syncthreads();
        #pragma unroll
        for (int i = 0; i < 16; i++) {
            if (srcs[i] >= 0) {
                int bkt = dsts[i] >> 8;
                int pos = atomicAdd(&lcur[bkt], 1);
                staging[pos] = ((uint_t)bkt << 24) | ((uint_t)(dsts[i] & 255) << 16)
                             | (uint_t)srcs[i];
            }
        }
        __syncthreads();
        if (t < NBKT) {
            int hcnt = hist[t];
            gbase[t] = t * BMAX + (hcnt ? atomicAdd(&bucketcur[t], hcnt) : 0);
        }
        __syncthreads();
        int tot = tot_s;
        for (int i = t; i < tot; i += 256) {
            uint_t e = staging[i];
            int bkt = e >> 24;
            arena[gbase[bkt] + (i - lofs[bkt])] = (int)(e & 0xFFFFFF);
        }
    } else if (blk < NBKT + NB_TEMP) {
        // ------- temporal, vectorized: 8 consecutive channels per thread ----
        int tid2 = (blk - NBKT) * 256 + t;     // 0..799999
        int rt   = tid2 >> 8;
        int kt   = (tid2 >> 6) & 3;
        int lane = tid2 & 63;
        int n  = rt * 16 + (lane & 15);
        int c0 = kt * 32 + (lane >> 4) * 8;
        float tv = ts[n];
        const float coef = -0.07195570687f;    // -ln(10000)/128
        float4 x0 = *reinterpret_cast<const float4*>(x + (size_t)n * 128 + c0);
        float4 x1 = *reinterpret_cast<const float4*>(x + (size_t)n * 128 + c0 + 4);
        float xv[8] = {x0.x, x0.y, x0.z, x0.w, x1.x, x1.y, x1.z, x1.w};
        uint_t hw[4];
        #pragma unroll
        for (int i = 0; i < 4; i++) {
            float ang = tv * __expf((float)(c0 + 2 * i) * coef);
            float sn, cs;
            __sincosf(ang, &sn, &cs);
            float v0 = xv[2 * i] + sn;
            float v1 = xv[2 * i + 1] + cs;
            uint_t pk;
            asm("v_cvt_pk_bf16_f32 %0, %1, %2" : "=v"(pk) : "v"(v0), "v"(v1));
            hw[i] = pk;
        }
        uint4 hp; hp.x = hw[0]; hp.y = hw[1]; hp.z = hw[2]; hp.w = hw[3];
        *reinterpret_cast<uint4*>(h + (size_t)tid2 * 8) = hp;
    } else if (blk < NBKT + NB_TEMP + NB_WS) {
        // ---------------- wsplit (Q weights+bias pre-scaled by 1/8) --------
        int tid = (blk - NBKT - NB_TEMP) * 256 + t;  // 0..131071
        int j    = tid & 7;
        int lane = (tid >> 3) & 63;
        int kt   = (tid >> 9) & 3;
        int cgy  = (tid >> 11) & 31;
        int L    = tid >> 16;
        int col = cgy * 16 + (lane & 15);
        int k   = kt * 32 + (lane >> 4) * 8 + j;
        int mat = col >> 7, c = col & 127;
        const float* W = (L == 0)
            ? ((mat == 0) ? Wq1 : (mat == 1) ? Wk1 : (mat == 2) ? Wv1 : Ws1)
            : ((mat == 0) ? Wq2 : (mat == 1) ? Wk2 : (mat == 2) ? Wv2 : Ws2);
        size_t base = (size_t)L * 65536 + (size_t)cgy * 2048 + (size_t)kt * 512;
        float wv = W[k * 128 + c];
        if (mat == 0) wv *= 0.125f;           // fold q-scale (exact in bf16)
        WF[base + lane * 8 + j] = f2bf(wv);
        if (kt == 0 && (lane >> 4) == 0 && j == 0) {
            const float* b = (L == 0)
                ? ((mat == 0) ? bq1 : (mat == 1) ? bk1 : (mat == 2) ? bv1 : bs1)
                : ((mat == 0) ? bq2 : (mat == 1) ? bk2 : (mat == 2) ? bv2 : bs2);
            float bb = b[c];
            if (mat == 0) bb *= 0.125f;
            bias_cat[L * 512 + col] = bb;
        }
    } else if (blk < NBKT + NB_TEMP + NB_WS + NGRAPH) {
        // ---------------- docemb ----------------
        int b = blk - NBKT - NB_TEMP - NB_WS;   // 0..63
        int c = t & 127, half = t >> 7;
        float* red = (float*)staging;           // reuse LDS
        float acc = (half == 0) ? bdoc[c] : 0.f;
        int k0 = half * 256;
        #pragma unroll 8
        for (int k = 0; k < 256; k++)
            acc += doc[b * 512 + k0 + k] * Wdoc[(size_t)(k0 + k) * 128 + c];
        red[t] = acc;
        __syncthreads();
        if (t < 128) docemb[b * 128 + c] = fmaxf(red[t] + red[t + 128], 0.f);
    } else {
        // ---------------- gstart scan (batch is sorted) ----------------
        int gblk = blk - NBKT - NB_TEMP - NB_WS - NGRAPH;  // 0..195
        int i = gblk * 256 + t;
        if (i < N_NODES) {
            int bi = batch[i];
            int bp = (i == 0) ? -1 : batch[i - 1];
            if (bi != bp) {
                for (int g = bp + 1; g <= bi; g++) gstart[g] = i;
            }
            if (i == N_NODES - 1) {
                for (int g = bi + 1; g <= NGRAPH; g++) gstart[g] = N_NODES;
            }
        }
    }
}

// ---------- shared gemm body: swapped-operand MFMA, vectorized epilogue -----
// Each wave: 2 row-tiles x 16 column-groups (256 cols). A loaded ONCE per
// wave (was 4x replicated across y); B streams from L2-resident WF.
__device__ __forceinline__ void gemm_body(
    int rp, int cg0, int lane,
    const ushort_t* __restrict__ hf, const ushort_t* __restrict__ WF,
    const float* __restrict__ bias_cat,
    ushort_t* __restrict__ qsb, uchar_t* __restrict__ kv8) {
    int rt0 = rp * 2;
    if (rt0 >= N_RT) return;
    int rt1 = rt0 + 1;
    int rt1c = (rt1 < N_RT) ? rt1 : rt0;

    short8 a0[4], a1[4];
    {
        const ushort_t* b0 = hf + (size_t)rt0 * 2048 + lane * 8;
        const ushort_t* b1 = hf + (size_t)rt1c * 2048 + lane * 8;
        #pragma unroll
        for (int kt = 0; kt < 4; kt++) {
            a0[kt] = *reinterpret_cast<const short8*>(b0 + kt * 512);
            a1[kt] = *reinterpret_cast<const short8*>(b1 + kt * 512);
        }
    }

    const ushort_t* wfl = WF + (size_t)cg0 * 2048 + lane * 8;
    short8 bh[4];
    #pragma unroll
    for (int kt = 0; kt < 4; kt++)
        bh[kt] = *reinterpret_cast<const short8*>(wfl + kt * 512);

    int m = lane & 15;        // node within tile (C col after swap)
    int quad = lane >> 4;     // channel quad   (C row group after swap)
    size_t node0 = (size_t)rt0 * 16 + m;
    size_t node1 = (size_t)rt1 * 16 + m;

    #pragma unroll 2
    for (int cg = 0; cg < 16; cg++) {
        short8 bn[4];
        if (cg < 15) {
            const ushort_t* fpn = wfl + (size_t)(cg + 1) * 2048;
            #pragma unroll
            for (int kt = 0; kt < 4; kt++)
                bn[kt] = *reinterpret_cast<const short8*>(fpn + kt * 512);
        }
        float4v acc0 = {0.f, 0.f, 0.f, 0.f};
        float4v acc1 = {0.f, 0.f, 0.f, 0.f};
        #pragma unroll
        for (int kt = 0; kt < 4; kt++) {
            acc0 = __builtin_amdgcn_mfma_f32_16x16x32_bf16(bh[kt], a0[kt], acc0, 0, 0, 0);
            acc1 = __builtin_amdgcn_mfma_f32_16x16x32_bf16(bh[kt], a1[kt], acc1, 0, 0, 0);
        }
        int col0 = (cg0 + cg) * 16;
        int chq = col0 + quad * 4;          // global column of acc[0]
        float4 b4 = *reinterpret_cast<const float4*>(bias_cat + chq);
        int mat = col0 >> 7;
        {
            float v0 = acc0[0] + b4.x, v1 = acc0[1] + b4.y;
            float v2 = acc0[2] + b4.z, v3 = acc0[3] + b4.w;
            if (mat == 0 || mat == 3) {
                uint_t lo, hi;
                asm("v_cvt_pk_bf16_f32 %0, %1, %2" : "=v"(lo) : "v"(v0), "v"(v1));
                asm("v_cvt_pk_bf16_f32 %0, %1, %2" : "=v"(hi) : "v"(v2), "v"(v3));
                int cq = (mat == 0) ? chq : (chq - 256);   // S -> [128,256)
                uint2 pk; pk.x = lo; pk.y = hi;
                *reinterpret_cast<uint2*>(qsb + node0 * 256 + cq) = pk;
            } else {
                int w = __builtin_amdgcn_cvt_pk_fp8_f32(v0, v1, 0, false);
                w = __builtin_amdgcn_cvt_pk_fp8_f32(v2, v3, w, true);
                *reinterpret_cast<uint_t*>(kv8 + node0 * 256 + (chq - 128)) = (uint_t)w;
            }
        }
        if (rt1 < N_RT) {
            float v0 = acc1[0] + b4.x, v1 = acc1[1] + b4.y;
            float v2 = acc1[2] + b4.z, v3 = acc1[3] + b4.w;
            if (mat == 0 || mat == 3) {
                uint_t lo, hi;
                asm("v_cvt_pk_bf16_f32 %0, %1, %2" : "=v"(lo) : "v"(v0), "v"(v1));
                asm("v_cvt_pk_bf16_f32 %0, %1, %2" : "=v"(hi) : "v"(v2), "v"(v3));
                int cq = (mat == 0) ? chq : (chq - 256);
                uint2 pk; pk.x = lo; pk.y = hi;
                *reinterpret_cast<uint2*>(qsb + node1 * 256 + cq) = pk;
            } else {
                int w = __builtin_amdgcn_cvt_pk_fp8_f32(v0, v1, 0, false);
                w = __builtin_amdgcn_cvt_pk_fp8_f32(v2, v3, w, true);
                *reinterpret_cast<uint_t*>(kv8 + node1 * 256 + (chq - 128)) = (uint_t)w;
            }
        }
        #pragma unroll
        for (int kt = 0; kt < 4; kt++) bh[kt] = bn[kt];
    }
}

// ---------- fused: passB (off+csr build) + gemm L1 + fusdoc -----------------
__global__ __launch_bounds__(256) void g1_kernel(
    int* __restrict__ off, const int* __restrict__ arena,
    const int* __restrict__ bucketcur, int* __restrict__ csr,
    const ushort_t* __restrict__ hf, const ushort_t* __restrict__ WF,
    const float* __restrict__ bias_cat,
    ushort_t* __restrict__ qsb, uchar_t* __restrict__ kv8,
    const float* __restrict__ docemb, const float* __restrict__ Wfus,
    const float* __restrict__ bfus, float* __restrict__ fusdoc) {
    __shared__ uint_t smem[BCAP + 1024];
    __shared__ int bbase_s;
    int blk = blockIdx.x;
    int t = threadIdx.x;
    if (blk < NBKT) {
        // ---- passB: derive off[] + exact csr from arena bucket ----
        uint_t* stage = smem;
        int* lcnt = (int*)(smem + BCAP);
        int* exc  = (int*)(smem + BCAP + 256);
        int* lcur = (int*)(smem + BCAP + 512);
        int* sb   = (int*)(smem + BCAP + 768);
        int bc = (t < NBKT) ? bucketcur[t] : 0;
        sb[t] = bc;
        __syncthreads();
        #pragma unroll
        for (int s = 1; s < 256; s <<= 1) {
            int a = (t >= s) ? sb[t - s] : 0;
            __syncthreads();
            sb[t] += a;
            __syncthreads();
        }
        if (t == 0) bbase_s = (blk == 0) ? 0 : sb[blk - 1];
        lcnt[t] = 0; lcur[t] = 0;
        __syncthreads();
        int bbase = bbase_s;
        int size = bucketcur[blk];
        int abase = blk * BMAX;
        int lim = (size < BCAP) ? size : BCAP;
        for (int i = t; i < lim; i += 256) stage[i] = (uint_t)arena[abase + i];
        __syncthreads();
        for (int i = t; i < size; i += 256) {
            uint_t e = (i < BCAP) ? stage[i] : (uint_t)arena[abase + i];
            atomicAdd(&lcnt[(e >> 16) & 255], 1);
        }
        __syncthreads();
        int v = lcnt[t];
        sb[t] = v;
        __syncthreads();
        #pragma unroll
        for (int s = 1; s < 256; s <<= 1) {
            int a = (t >= s) ? sb[t - s] : 0;
            __syncthreads();
            sb[t] += a;
            __syncthreads();
        }
        exc[t] = sb[t] - v;
        int n0 = blk * 256;
        if (n0 + t < N_NODES) off[n0 + t] = bbase + sb[t] - v;
        if (blk == NBKT - 1 && t == 0) off[N_NODES] = N_EDGES;
        __syncthreads();
        for (int i = t; i < size; i += 256) {
            uint_t e = (i < BCAP) ? stage[i] : (uint_t)arena[abase + i];
            int dlow = (e >> 16) & 255;
            int src = (int)(e & 0xFFFF);
            int pos = exc[dlow] + atomicAdd(&lcur[dlow], 1);
            csr[bbase + pos] = src << 8;   // byte offset into kv8
        }
    } else if (blk < NBKT + NB_GEMM) {
        int blk2 = blk - NBKT;           // 0..781
        int y = blk2 / 391, bx = blk2 % 391;
        int wave = t >> 6, lane = t & 63;
        gemm_body(bx * 4 + wave, y * 16, lane, hf, WF, bias_cat, qsb, kv8);
    } else {
        // ---- fusdoc[b][c] = bfus[c] + docemb[b] @ Wfus[128:256] ----
        int b = blk - NBKT - NB_GEMM;    // 0..63
        int c = t & 127, half = t >> 7;
        float* de = (float*)smem;
        float* red = (float*)smem + 128;
        if (t < 128) de[t] = docemb[b * 128 + t];
        __syncthreads();
        float acc = (half == 0) ? bfus[c] : 0.f;
        int k0 = half * 64;
        #pragma unroll 8
        for (int k = 0; k < 64; k++)
            acc += de[k0 + k] * Wfus[(size_t)(128 + k0 + k) * 128 + c];
        red[t] = acc;
        __syncthreads();
        if (t < 128) fusdoc[b * 128 + c] = red[t] + red[t + 128];
    }
}

// ---------- plain gemm (layer 2) ----------
__global__ __launch_bounds__(256) void gemm_qkvs(
    const ushort_t* __restrict__ hf,
    const ushort_t* __restrict__ WF,
    const float* __restrict__ bias_cat,
    ushort_t* __restrict__ qsb, uchar_t* __restrict__ kv8) {
    int t = threadIdx.x;
    int wave = t >> 6, lane = t & 63;
    gemm_body(blockIdx.x * 4 + wave, blockIdx.y * 16, lane,
              hf, WF, bias_cat, qsb, kv8);
}

// ---------- fused per-node attention + skip + BN + relu -> h (frag-major) ----
// csr_src holds src*256 (byte offset). 16 lanes/edge, 8 edges/iter, K/V data
// prefetched one iteration ahead, packed-f32 math. (R4-proven version.)
__global__ __launch_bounds__(256) void node_attn_bn(
    const int* __restrict__ off, const int* __restrict__ csr_src,
    const ushort_t* __restrict__ qsb, const uchar_t* __restrict__ kv8,
    const float* __restrict__ bng, const float* __restrict__ bnb,
    const float* __restrict__ bnm, const float* __restrict__ bnv,
    ushort_t* __restrict__ h) {
    int wave = threadIdx.x >> 6;
    int n = blockIdx.x * 4 + wave;
    if (n >= N_NODES) return;
    int lane = threadIdx.x & 63;
    int qtr = lane >> 4, s16 = lane & 15;
    int c0 = s16 * 8;

    const ushort_t* row_qs = qsb + (size_t)n * 256;
    float2v q2[4];
    {
        uint4 qu = *reinterpret_cast<const uint4*>(row_qs + c0);
        q2[0].x = bf2f(qu.x & 0xffff); q2[0].y = bf2f(qu.x >> 16);
        q2[1].x = bf2f(qu.y & 0xffff); q2[1].y = bf2f(qu.y >> 16);
        q2[2].x = bf2f(qu.z & 0xffff); q2[2].y = bf2f(qu.z >> 16);
        q2[3].x = bf2f(qu.w & 0xffff); q2[3].y = bf2f(qu.w >> 16);
    }

    int e0 = off[n], e1 = off[n + 1];
    float l = 0.f;
    float2v o2[4];
    o2[0] = (float2v){0.f, 0.f}; o2[1] = (float2v){0.f, 0.f};
    o2[2] = (float2v){0.f, 0.f}; o2[3] = (float2v){0.f, 0.f};

    int src_a = (e0 + qtr < e1) ? csr_src[e0 + qtr] : 0;
    int src_b = (e0 + 4 + qtr < e1) ? csr_src[e0 + 4 + qtr] : 0;
    uint2 kua, vua, kub, vub;
    {
        const uchar_t* kpa = kv8 + (uint_t)src_a;
        const uchar_t* kpb = kv8 + (uint_t)src_b;
        kua = *reinterpret_cast<const uint2*>(kpa + c0);
        vua = *reinterpret_cast<const uint2*>(kpa + 128 + c0);
        kub = *reinterpret_cast<const uint2*>(kpb + c0);
        vub = *reinterpret_cast<const uint2*>(kpb + 128 + c0);
    }

    for (int p = e0; p < e1; p += 8) {
        bool va = (p + qtr) < e1, vb = (p + 4 + qtr) < e1;
        int na = p + 8 + qtr, nb = p + 12 + qtr;
        int nsa = (na < e1) ? csr_src[na] : 0;
        int nsb = (nb < e1) ? csr_src[nb] : 0;
        const uchar_t* kpa_n = kv8 + (uint_t)nsa;
        const uchar_t* kpb_n = kv8 + (uint_t)nsb;
        uint2 kua_n = *reinterpret_cast<const uint2*>(kpa_n + c0);
        uint2 vua_n = *reinterpret_cast<const uint2*>(kpa_n + 128 + c0);
        uint2 kub_n = *reinterpret_cast<const uint2*>(kpb_n + c0);
        uint2 vub_n = *reinterpret_cast<const uint2*>(kpb_n + 128 + c0);

        float2v ka2[4], wa2[4], kb2[4], wb2[4];
        fp8x4_dec2(kua.x, ka2);  fp8x4_dec2(kua.y, ka2 + 2);
        fp8x4_dec2(kub.x, kb2);  fp8x4_dec2(kub.y, kb2 + 2);
        fp8x4_dec2(vua.x, wa2);  fp8x4_dec2(vua.y, wa2 + 2);
        fp8x4_dec2(vub.x, wb2);  fp8x4_dec2(vub.y, wb2 + 2);

        float2v da2 = pk_mul(q2[0], ka2[0]);
        float2v db2 = pk_mul(q2[0], kb2[0]);
        da2 = pk_fma(q2[1], ka2[1], da2);  db2 = pk_fma(q2[1], kb2[1], db2);
        da2 = pk_fma(q2[2], ka2[2], da2);  db2 = pk_fma(q2[2], kb2[2], db2);
        da2 = pk_fma(q2[3], ka2[3], da2);  db2 = pk_fma(q2[3], kb2[3], db2);
        float da = da2.x + da2.y;
        float db = db2.x + db2.y;
        da += __shfl_xor(da, 1);  db += __shfl_xor(db, 1);
        da += __shfl_xor(da, 2);  db += __shfl_xor(db, 2);
        da += __shfl_xor(da, 4);  db += __shfl_xor(db, 4);
        float pea = va ? __expf(da) : 0.f;
        float peb = vb ? __expf(db) : 0.f;
        l += pea + peb;
        float2v pa; pa.x = pea; pa.y = pea;
        float2v pb; pb.x = peb; pb.y = peb;
        #pragma unroll
        for (int i = 0; i < 4; i++) {
            o2[i] = pk_fma(pa, wa2[i], o2[i]);
            o2[i] = pk_fma(pb, wb2[i], o2[i]);
        }
        kua = kua_n; vua = vua_n; kub = kub_n; vub = vub_n;
    }
    #pragma unroll
    for (int offx = 16; offx <= 32; offx <<= 1) {
        l += __shfl_xor(l, offx);
        #pragma unroll
        for (int i = 0; i < 4; i++) {
            o2[i].x += __shfl_xor(o2[i].x, offx);
            o2[i].y += __shfl_xor(o2[i].y, offx);
        }
    }

    if (qtr == 0) {
        float inv = 1.f / (l + 1e-16f);
        float o[8] = {o2[0].x, o2[0].y, o2[1].x, o2[1].y,
                      o2[2].x, o2[2].y, o2[3].x, o2[3].y};
        float sv[8];
        {
            uint4 su = *reinterpret_cast<const uint4*>(row_qs + 128 + c0);
            sv[0] = bf2f(su.x & 0xffff); sv[1] = bf2f(su.x >> 16);
            sv[2] = bf2f(su.y & 0xffff); sv[3] = bf2f(su.y >> 16);
            sv[4] = bf2f(su.z & 0xffff); sv[5] = bf2f(su.z >> 16);
            sv[6] = bf2f(su.w & 0xffff); sv[7] = bf2f(su.w >> 16);
        }
        float gv[8], bv[8], mv[8], vr[8];
        *reinterpret_cast<float4*>(gv)     = *reinterpret_cast<const float4*>(bng + c0);
        *reinterpret_cast<float4*>(gv + 4) = *reinterpret_cast<const float4*>(bng + c0 + 4);
        *reinterpret_cast<float4*>(bv)     = *reinterpret_cast<const float4*>(bnb + c0);
        *reinterpret_cast<float4*>(bv + 4) = *reinterpret_cast<const float4*>(bnb + c0 + 4);
        *reinterpret_cast<float4*>(mv)     = *reinterpret_cast<const float4*>(bnm + c0);
        *reinterpret_cast<float4*>(mv + 4) = *reinterpret_cast<const float4*>(bnm + c0 + 4);
        *reinterpret_cast<float4*>(vr)     = *reinterpret_cast<const float4*>(bnv + c0);
        *reinterpret_cast<float4*>(vr + 4) = *reinterpret_cast<const float4*>(bnv + c0 + 4);
        uint_t hw[4];
        #pragma unroll
        for (int i = 0; i < 8; i++) {
            float val = fmaxf(o[i] * inv + sv[i], 0.f);
            val = (val - mv[i]) * rsqrtf(vr[i] + 1e-5f) * gv[i] + bv[i];
            val = fmaxf(val, 0.f);
            ushort_t hb = f2bf(val);
            if (i & 1) hw[i >> 1] |= (uint_t)hb << 16;
            else       hw[i >> 1] = hb;
        }
        int rt = n >> 4, mnode = n & 15;
        int kt = s16 >> 2, qd = s16 & 3;
        size_t fidx = (size_t)rt * 2048 + kt * 512 + (mnode + 16 * qd) * 8;
        uint4 hp; hp.x = hw[0]; hp.y = hw[1]; hp.z = hw[2]; hp.w = hw[3];
        *reinterpret_cast<uint4*>(h + fidx) = hp;
    }
}

// ---------- merged pool + final head (batch sorted -> per-graph ranges) -----
__global__ __launch_bounds__(256) void final_pool(
    const ushort_t* __restrict__ h, const int* __restrict__ gstart,
    const float* __restrict__ fusdoc, const float* __restrict__ Wfus,
    const float* __restrict__ Wtask, const float* __restrict__ btask,
    const float* __restrict__ Wtime, const float* __restrict__ btime,
    float* __restrict__ out) {
    __shared__ float lsum[16][136];
    __shared__ float gbuf[128], fbuf[128], red[256];
    int b = blockIdx.x, t = threadIdx.x;
    int r0 = gstart[b], r1 = gstart[b + 1];
    int o = t & 15, s = t >> 4;       // o: channel octet, s: node slot
    int kt = o >> 2, qd = o & 3;
    float f0 = 0, f1 = 0, f2 = 0, f3 = 0, f4 = 0, f5 = 0, f6 = 0, f7 = 0;
    for (int n = r0 + s; n < r1; n += 16) {
        int rt = n >> 4, mn = n & 15;
        uint4 d = *reinterpret_cast<const uint4*>(
            h + (size_t)rt * 2048 + kt * 512 + (mn + 16 * qd) * 8);
        f0 += bf2f(d.x & 0xffff); f1 += bf2f(d.x >> 16);
        f2 += bf2f(d.y & 0xffff); f3 += bf2f(d.y >> 16);
        f4 += bf2f(d.z & 0xffff); f5 += bf2f(d.z >> 16);
        f6 += bf2f(d.w & 0xffff); f7 += bf2f(d.w >> 16);
    }
    int c0 = kt * 32 + qd * 8;
    float* dst = &lsum[s][c0];
    dst[0] = f0; dst[1] = f1; dst[2] = f2; dst[3] = f3;
    dst[4] = f4; dst[5] = f5; dst[6] = f6; dst[7] = f7;
    __syncthreads();
    if (t < 128) {
        float a = 0.f;
        #pragma unroll
        for (int i = 0; i < 16; i++) a += lsum[i][t];
        gbuf[t] = a / fmaxf((float)(r1 - r0), 1.f);
    }
    __syncthreads();
    int c = t & 127, half = t >> 7;
    float f = (half == 0) ? fusdoc[b * 128 + c] : 0.f;
    int k0 = half * 64;
    #pragma unroll 8
    for (int k = 0; k < 64; k++)
        f += gbuf[k0 + k] * Wfus[(size_t)(k0 + k) * 128 + c];
    red[t] = f;
    __syncthreads();
    if (t < 128) fbuf[t] = fmaxf(red[t] + red[t + 128], 0.f);
    __syncthreads();
    if (t < 16) {
        float a = btask[t];
        #pragma unroll 8
        for (int k = 0; k < 128; k++) a += fbuf[k] * Wtask[k * 16 + t];
        out[b * 16 + t] = a;
    } else if (t == 16) {
        float a = btime[0];
        #pragma unroll 8
        for (int k = 0; k < 128; k++) a += fbuf[k] * Wtime[k];
        out[NGRAPH * 16 + b] = a;
    }
}

extern "C" void kernel_launch(void* const* d_in, const int* in_sizes, int n_in,
                              void* d_out, int out_size, void* d_ws, size_t ws_size,
                              hipStream_t stream) {
    (void)in_sizes; (void)n_in; (void)out_size; (void)ws_size;
    const float* x    = (const float*)d_in[0];
    const int*   ei   = (const int*)d_in[1];
    const int*   batch= (const int*)d_in[2];
    const float* ts   = (const float*)d_in[3];
    const float* doc  = (const float*)d_in[4];
    const float* Wq1  = (const float*)d_in[5];
    const float* bq1  = (const float*)d_in[6];
    const float* Wk1  = (const float*)d_in[7];
    const float* bk1  = (const float*)d_in[8];
    const float* Wv1  = (const float*)d_in[9];
    const float* bv1  = (const float*)d_in[10];
    const float* Ws1  = (const float*)d_in[11];
    const float* bs1  = (const float*)d_in[12];
    const float* Wq2  = (const float*)d_in[13];
    const float* bq2  = (const float*)d_in[14];
    const float* Wk2  = (const float*)d_in[15];
    const float* bk2  = (const float*)d_in[16];
    const float* Wv2  = (const float*)d_in[17];
    const float* bv2  = (const float*)d_in[18];
    const float* Ws2  = (const float*)d_in[19];
    const float* bs2  = (const float*)d_in[20];
    const float* bn1g = (const float*)d_in[21];
    const float* bn1b = (const float*)d_in[22];
    const float* bn1m = (const float*)d_in[23];
    const float* bn1v = (const float*)d_in[24];
    const float* bn2g = (const float*)d_in[25];
    const float* bn2b = (const float*)d_in[26];
    const float* bn2m = (const float*)d_in[27];
    const float* bn2v = (const float*)d_in[28];
    const float* Wdoc = (const float*)d_in[29];
    const float* bdoc = (const float*)d_in[30];
    const float* Wfus = (const float*)d_in[31];
    const float* bfus = (const float*)d_in[32];
    const float* Wtask= (const float*)d_in[33];
    const float* btask= (const float*)d_in[34];
    const float* Wtime= (const float*)d_in[35];
    const float* btime= (const float*)d_in[36];

    char* ws = (char*)d_ws;
    ushort_t* h      = (ushort_t*)(ws + 0);           // 12.8 MB
    ushort_t* qsb    = (ushort_t*)(ws + 12800000);    // 25.6 MB
    uchar_t*  kv8    = (uchar_t*)(ws + 38400000);     // 12.8 MB
    ushort_t* WF     = (ushort_t*)(ws + 51200000);    // 256 KB
    float*    biasc  = (float*)(ws + 51462144);       // 4 KB
    int*      gstart = (int*)(ws + 51466240);         // 260 B
    int*      off    = (int*)(ws + 51499264);         // 200004 B
    int*      bucketcur = (int*)(ws + 51699268);      // 784 B
    int*      arena  = (int*)(ws + 51700052);         // 196*8192*4 = 6.42 MB
    int*      csr    = (int*)(ws + 58122580);         // 3.2 MB
    float*    docemb = (float*)(ws + 61322580);       // 32 KB
    float*    fusdoc = (float*)(ws + 61355348);       // 32 KB

    float* out = (float*)d_out;

    hipMemsetAsync(bucketcur, 0, 784, stream);

    prep_kernel<<<NBKT + NB_TEMP + NB_WS + NGRAPH + NB_GS, 256, 0, stream>>>(
        ei, bucketcur, arena, x, ts, h,
        Wq1, Wk1, Wv1, Ws1, Wq2, Wk2, Wv2, Ws2,
        bq1, bk1, bv1, bs1, bq2, bk2, bv2, bs2, WF, biasc,
        doc, Wdoc, bdoc, docemb, batch, gstart);

    const size_t WF_LAYER = 65536;  // shorts per layer

    // ---- layer 1 (gemm fused with passB(off+csr) + fusdoc) ----
    g1_kernel<<<NBKT + NB_GEMM + NGRAPH, 256, 0, stream>>>(
        off, arena, bucketcur, csr, h, WF, biasc, qsb, kv8,
        docemb, Wfus, bfus, fusdoc);
    node_attn_bn<<<12500, 256, 0, stream>>>(off, csr, qsb, kv8, bn1g, bn1b, bn1m, bn1v, h);

    // ---- layer 2 ----
    gemm_qkvs<<<dim3(391, 2), 256, 0, stream>>>(h, WF + WF_LAYER, biasc + 512, qsb, kv8);
    node_attn_bn<<<12500, 256, 0, stream>>>(off, csr, qsb, kv8, bn2g, bn2b, bn2m, bn2v, h);

    // ---- merged pool + final head ----
    final_pool<<<NGRAPH, 256, 0, stream>>>(h, gstart, fusdoc, Wfus,
                                           Wtask, btask, Wtime, btime, out);
}